// Round 2
// baseline (1729.799 us; speedup 1.0000x reference)
//
#include <hip/hip_runtime.h>
#include <math.h>

// ---------------- complex helpers (float2 = re,im) ----------------
typedef float2 cf;

__device__ __forceinline__ cf mkc(float x, float y){ return make_float2(x,y); }

// acc += a*b
__device__ __forceinline__ void cmad(cf& acc, cf a, cf b){
    acc.x = fmaf(a.x, b.x, fmaf(-a.y, b.y, acc.x));
    acc.y = fmaf(a.x, b.y, fmaf( a.y, b.x, acc.y));
}
// acc += conj(a)*b
__device__ __forceinline__ void cmadc(cf& acc, cf a, cf b){
    acc.x = fmaf(a.x, b.x, fmaf( a.y, b.y, acc.x));
    acc.y = fmaf(a.x, b.y, fmaf(-a.y, b.x, acc.y));
}
// acc += a*conj(b)
__device__ __forceinline__ void cmad_bc(cf& acc, cf a, cf b){
    acc.x = fmaf(a.x, b.x, fmaf( a.y, b.y, acc.x));
    acc.y = fmaf(a.y, b.x, fmaf(-a.x, b.y, acc.y));
}
// principal complex sqrt (numpy branch conventions)
__device__ __forceinline__ cf csqrtf2(cf z){
    float x = z.x, y = z.y;
    float r = hypotf(x, y);
    if (r == 0.0f) return mkc(0.f, 0.f);
    if (x >= 0.0f){
        float t = sqrtf(0.5f*(r + x));
        return mkc(t, 0.5f*y/t);
    } else {
        float t = sqrtf(0.5f*(r - x));
        return mkc(0.5f*fabsf(y)/t, copysignf(t, y));
    }
}
// a / b
__device__ __forceinline__ cf cdiv(cf a, cf b){
    float inv = 1.0f/(b.x*b.x + b.y*b.y);
    return mkc((a.x*b.x + a.y*b.y)*inv, (a.y*b.x - a.x*b.y)*inv);
}

#define LN2F  0.69314718055994530942f
#define BETA_ 0.9f
#define OMB_  0.1f
#define EPS_  1e-8f
#define ETAF_ 0.01f
#define ETAW_ 0.01f

__device__ __forceinline__ float readScalarF(const int* p){
    int iv = *p;
    if (iv >= 0 && iv < 1000000) return (float)iv;
    return __int_as_float(iv);
}
__device__ __forceinline__ int readScalarI(const int* p){
    int iv = *p;
    if (iv >= 0 && iv < 1000000) return iv;
    return (int)(__int_as_float(iv) + 0.5f);
}

__device__ __forceinline__ float blockReduceSum(float v, float* sRed, float* sBcast, int tid){
    #pragma unroll
    for (int o = 32; o > 0; o >>= 1) v += __shfl_down(v, o, 64);
    if ((tid & 63) == 0) sRed[tid >> 6] = v;
    __syncthreads();
    if (tid == 0) *sBcast = sRed[0] + sRed[1] + sRed[2] + sRed[3];
    __syncthreads();
    return *sBcast;
}

// ---------------- optional prep: Mm = A_dot^H @ R_N_inv @ A_dot (64x64) -> ws ----------------
// Chunked: LDS = 32KB (A) + 4KB (T chunk) = 36KB, safely under any limit.
__global__ __launch_bounds__(256) void pga_prep(
    const float* __restrict__ Ar, const float* __restrict__ Ai,
    const float* __restrict__ Rr, const float* __restrict__ Ri,
    cf* __restrict__ Mm)
{
    __shared__ cf sA[4096];   // [q][i] row-major, unpadded
    __shared__ cf Tc[512];    // [p][jc] 64x8
    int tid = threadIdx.x;
    for (int idx = tid; idx < 4096; idx += 256)
        sA[idx] = mkc(Ar[idx], Ai[idx]);
    __syncthreads();
    for (int jb = 0; jb < 8; jb++){
        int j0 = jb*8;
        #pragma unroll
        for (int rep = 0; rep < 2; rep++){
            int idx = tid + rep*256;       // 512 elems
            int p = idx >> 3, jc = idx & 7;
            cf acc = mkc(0,0);
            for (int q = 0; q < 64; q++){
                cf rv = mkc(Rr[p*64+q], Ri[p*64+q]);
                cmad(acc, rv, sA[q*64 + j0 + jc]);
            }
            Tc[idx] = acc;
        }
        __syncthreads();
        #pragma unroll
        for (int rep = 0; rep < 2; rep++){
            int idx = tid + rep*256;
            int i = idx >> 3, jc = idx & 7;
            cf acc = mkc(0,0);
            for (int p = 0; p < 64; p++)
                cmadc(acc, sA[p*64+i], Tc[p*8+jc]);
            Mm[i*64 + j0 + jc] = acc;
        }
        __syncthreads();
    }
}

// ---------------- main kernel: full PGA per batch element ----------------
// dims: Mu=8, N=64, R=16.  LDS: 33.3KB (Mm) + 44.6KB pool (overlaid) ~ 78KB -> 2 blocks/CU
__global__ __launch_bounds__(256) void pga_main(
    const float* __restrict__ Hre, const float* __restrict__ Him,
    const float* __restrict__ F0re, const float* __restrict__ F0im,
    const float* __restrict__ W0re, const float* __restrict__ W0im,
    const float* __restrict__ Ar, const float* __restrict__ Ai,
    const float* __restrict__ Rr, const float* __restrict__ Ri,
    const cf* __restrict__ MmGlobal,
    const float* __restrict__ xi0p,
    const int* __restrict__ Ptp, const int* __restrict__ noutp, const int* __restrict__ ninnp,
    float* __restrict__ out, int B, int cplx)
{
    const int tid = threadIdx.x;
    const int b = blockIdx.x;

    __shared__ cf sMm[64*65];                 // padded rows
    __shared__ __align__(16) char sPool[44608];
    __shared__ cf sCoefC[8];
    __shared__ float sCoefA[8];
    __shared__ float sRate[8];
    __shared__ float sRed[4];
    __shared__ float sBcast;

    // pool layout (main phase)
    cf* sH    = (cf*)(sPool + 0);       // 8x65   (4160 B)
    cf* sF    = (cf*)(sPool + 4160);    // 64x17  (8704 B)
    cf* sSF   = (cf*)(sPool + 12864);   // 64x16  (8192 B)
    cf* sMF   = (cf*)(sPool + 21056);   // 64x17  (8704 B)
    cf* sW    = (cf*)(sPool + 29760);   // 16x8   (1024 B)
    cf* sSW   = (cf*)(sPool + 30784);   // 16x8
    cf* sV    = (cf*)(sPool + 31808);   // 16x16  (2048 B)
    cf* sU    = (cf*)(sPool + 33856);   // 8x16   (1024 B)
    cf* sT2   = (cf*)(sPool + 34880);   // 8x16
    cf* sRow  = (cf*)(sPool + 35904);   // 8x16 / 16x8
    cf* sVm   = (cf*)(sPool + 36928);   // 8x16
    cf* sFHMF = (cf*)(sPool + 37952);   // 16x16  (2048 B)
    cf* sFW   = (cf*)(sPool + 40000);   // 64x8   (4096 B)
    cf* sS    = (cf*)(sPool + 44096);   // 8x8    (512 B)

    const float Pt    = readScalarF(Ptp);
    const int n_outer = readScalarI(noutp);
    const int n_inner = readScalarI(ninnp);
    const float xi0   = xi0p[0];
    const int nt = n_outer * (n_inner + 1);

    float* outR = out;
    float* outC = out + (size_t)B * nt;
    float* outF = out + (size_t)2 * B * nt;
    float* outW = outF + (cplx ? (size_t)B * 2048 : (size_t)B * 1024);

    // ---- phase 0: Mm into LDS (from ws, or computed per-block with overlay scratch) ----
    if (MmGlobal){
        for (int idx = tid; idx < 4096; idx += 256){
            int r = idx >> 6, c = idx & 63;
            sMm[r*65+c] = MmGlobal[idx];
        }
    } else {
        cf* sA = (cf*)(sPool + 0);       // 64x64 = 32768 B (overlay)
        cf* Tc = (cf*)(sPool + 32768);   // 64x8  =  4096 B (overlay)
        for (int idx = tid; idx < 4096; idx += 256)
            sA[idx] = mkc(Ar[idx], Ai[idx]);
        __syncthreads();
        for (int jb = 0; jb < 8; jb++){
            int j0 = jb*8;
            #pragma unroll
            for (int rep = 0; rep < 2; rep++){
                int idx = tid + rep*256;
                int p = idx >> 3, jc = idx & 7;
                cf acc = mkc(0,0);
                for (int q = 0; q < 64; q++){
                    cf rv = mkc(Rr[p*64+q], Ri[p*64+q]);
                    cmad(acc, rv, sA[q*64 + j0 + jc]);
                }
                Tc[idx] = acc;
            }
            __syncthreads();
            #pragma unroll
            for (int rep = 0; rep < 2; rep++){
                int idx = tid + rep*256;
                int i = idx >> 3, jc = idx & 7;
                cf acc = mkc(0,0);
                for (int p = 0; p < 64; p++)
                    cmadc(acc, sA[p*64+i], Tc[p*8+jc]);
                sMm[i*65 + j0 + jc] = acc;
            }
            __syncthreads();
        }
    }
    __syncthreads();

    // ---- load H, F (unit-modulus projected), W; zero s_F, s_W ----
    {
        const float* hr = Hre + (size_t)b*512;
        const float* hi = Him + (size_t)b*512;
        for (int idx = tid; idx < 512; idx += 256){
            int m = idx >> 6, n = idx & 63;
            sH[m*65+n] = mkc(hr[idx], hi[idx]);
        }
        const float* fr = F0re + (size_t)b*1024;
        const float* fi = F0im + (size_t)b*1024;
        for (int idx = tid; idx < 1024; idx += 256){
            int n = idx >> 4, r = idx & 15;
            float re = fr[idx], im = fi[idx];
            float mag = hypotf(re, im);
            cf f = (mag > 1e-12f) ? mkc(re/mag, im/mag) : mkc(0.f, 0.f);
            sF[n*17+r] = f;
            sSF[idx] = mkc(0.f, 0.f);
        }
        if (tid < 128){
            sW[tid]  = mkc(W0re[(size_t)b*128 + tid], W0im[(size_t)b*128 + tid]);
            sSW[tid] = mkc(0.f, 0.f);
        }
    }
    __syncthreads();

    // ---- initial normalize: W *= sqrt(Pt / ||F@W||^2) ----
    {
        float part = 0.f;
        #pragma unroll
        for (int rep = 0; rep < 2; rep++){
            int idx = tid + rep*256; int n = idx >> 3, k = idx & 7;
            cf acc = mkc(0,0);
            for (int r = 0; r < 16; r++) cmad(acc, sF[n*17+r], sW[r*8+k]);
            part += acc.x*acc.x + acc.y*acc.y;
        }
        float pw = blockReduceSum(part, sRed, &sBcast, tid);
        float s0 = sqrtf(Pt / pw);
        if (tid < 128){ cf w = sW[tid]; sW[tid] = mkc(w.x*s0, w.y*s0); }
    }
    __syncthreads();

    for (int ii = 0; ii < n_outer; ii++){
        // V = W W^H
        {
            int i = tid >> 4, j = tid & 15;
            cf acc = mkc(0,0);
            for (int k = 0; k < 8; k++) cmad_bc(acc, sW[i*8+k], sW[j*8+k]);
            sV[tid] = acc;
        }
        __syncthreads();

        for (int jj = 0; jj < n_inner; jj++){
            // P1: MF = Mm@F ; u = conj(H)@F
            #pragma unroll
            for (int rep = 0; rep < 4; rep++){
                int idx = tid + rep*256; int n = idx >> 4, j = idx & 15;
                cf acc = mkc(0,0);
                for (int kk = 0; kk < 64; kk++) cmad(acc, sMm[n*65+kk], sF[kk*17+j]);
                sMF[n*17+j] = acc;
            }
            if (tid < 128){
                int m = tid >> 4, j = tid & 15;
                cf acc = mkc(0,0);
                for (int n = 0; n < 64; n++) cmadc(acc, sH[m*65+n], sF[n*17+j]);
                sU[tid] = acc;
            }
            __syncthreads();
            // P2: FHMF = F^H MF (+ trace partial) ; t2 = u@V
            float ptr_;
            {
                int i = tid >> 4, j = tid & 15;
                cf acc = mkc(0,0);
                for (int n = 0; n < 64; n++) cmadc(acc, sF[n*17+i], sMF[n*17+j]);
                sFHMF[tid] = acc;
                cf v = sV[j*16+i];
                ptr_ = acc.x*v.x - acc.y*v.y;
            }
            if (tid < 128){
                int m = tid >> 4, j = tid & 15;
                cf acc = mkc(0,0);
                for (int r = 0; r < 16; r++) cmad(acc, sU[m*16+r], sV[r*16+j]);
                sT2[tid] = acc;
            }
            float tr = blockReduceSum(ptr_, sRed, &sBcast, tid);
            // P4: per-user scalar coefs of grad_F_com
            if (tid < 8){
                int m = tid;
                float qf1 = 0.f; cf c = mkc(0,0);
                for (int j = 0; j < 16; j++){
                    cf t = sT2[m*16+j], u = sU[m*16+j];
                    qf1 += t.x*u.x + t.y*u.y;
                    cmad(c, u, sW[j*8+m]);
                }
                float qf2 = qf1 - (c.x*c.x + c.y*c.y);
                float inv1 = 1.0f/(LN2F*(qf1 + 1.0f) + 1e-4f);
                float inv2 = 1.0f/(LN2F*(qf2 + 1.0f) + 1e-4f);
                sCoefA[m] = inv1 - inv2;
                sCoefC[m] = mkc(c.x*inv2, c.y*inv2);
            }
            __syncthreads();
            // P5: row_m[j] = t2*(1/d1-1/d2) + (c/d2)*conj(W[j,m])
            if (tid < 128){
                int m = tid >> 4, j = tid & 15;
                cf t = sT2[tid];
                float a = sCoefA[m];
                cf row = mkc(t.x*a, t.y*a);
                cmad_bc(row, sCoefC[m], sW[j*8+m]);
                sRow[tid] = row;
            }
            __syncthreads();
            // P6: gF = 0.5*(MF@V)/tr + sum_m H[m,n]*row_m[j] ; RMSProp F update
            {
                float hinv = 0.5f / tr;
                #pragma unroll
                for (int rep = 0; rep < 4; rep++){
                    int idx = tid + rep*256; int n = idx >> 4, j = idx & 15;
                    cf acc = mkc(0,0);
                    for (int r = 0; r < 16; r++) cmad(acc, sMF[n*17+r], sV[r*16+j]);
                    cf g = mkc(acc.x*hinv, acc.y*hinv);
                    for (int m = 0; m < 8; m++) cmad(g, sH[m*65+n], sRow[m*16+j]);
                    cf sf = sSF[idx];
                    sf.x = BETA_*sf.x + OMB_*g.x;
                    sf.y = BETA_*sf.y + OMB_*g.y;
                    sSF[idx] = sf;
                    cf d = csqrtf2(sf); d.x += EPS_;
                    cf upd = cdiv(g, d);
                    cf f = sF[n*17+j];
                    f.x = fmaf(ETAF_, upd.x, f.x);
                    f.y = fmaf(ETAF_, upd.y, f.y);
                    sF[n*17+j] = f;
                }
            }
            __syncthreads();
            // P7: FW = F@W, power -> s
            float part = 0.f;
            #pragma unroll
            for (int rep = 0; rep < 2; rep++){
                int idx = tid + rep*256; int n = idx >> 3, k = idx & 7;
                cf acc = mkc(0,0);
                for (int r = 0; r < 16; r++) cmad(acc, sF[n*17+r], sW[r*8+k]);
                sFW[idx] = acc;
                part += acc.x*acc.x + acc.y*acc.y;
            }
            float pw = blockReduceSum(part, sRed, &sBcast, tid);
            float s = sqrtf(Pt / pw);
            // P8: crb trace (pre-scale) ; T = conj(H)@F (pre-scale)
            float ptrc = 0.f;
            #pragma unroll
            for (int rep = 0; rep < 2; rep++){
                int idx = tid + rep*256; int n = idx >> 3, k = idx & 7;
                cf acc = mkc(0,0);
                for (int kk = 0; kk < 64; kk++) cmad(acc, sMm[n*65+kk], sFW[kk*8+k]);
                cf fw = sFW[idx];
                ptrc += fw.x*acc.x + fw.y*acc.y;
            }
            if (tid < 128){
                int m = tid >> 4, j = tid & 15;
                cf acc = mkc(0,0);
                for (int n = 0; n < 64; n++) cmadc(acc, sH[m*65+n], sF[n*17+j]);
                sU[tid] = acc;
            }
            float trc = blockReduceSum(ptrc, sRed, &sBcast, tid);
            // P9: scale F ; S = s*(T@W)
            #pragma unroll
            for (int rep = 0; rep < 4; rep++){
                int idx = tid + rep*256; int n = idx >> 4, j = idx & 15;
                cf f = sF[n*17+j];
                sF[n*17+j] = mkc(f.x*s, f.y*s);
            }
            if (tid < 64){
                int m = tid >> 3, k = tid & 7;
                cf acc = mkc(0,0);
                for (int j2 = 0; j2 < 16; j2++) cmad(acc, sU[m*16+j2], sW[j2*8+k]);
                sS[tid] = mkc(acc.x*s, acc.y*s);
            }
            __syncthreads();
            // P10: rates
            if (tid < 8){
                int m = tid;
                float tot = 0.f, sig = 0.f;
                for (int k = 0; k < 8; k++){
                    cf v = sS[m*8+k];
                    float p = v.x*v.x + v.y*v.y;
                    tot += p; if (k == m) sig = p;
                }
                sRate[m] = log2f(1.0f + sig/((tot - sig) + 1.0f));
            }
            __syncthreads();
            if (tid == 0){
                float rate = 0.f;
                for (int m = 0; m < 8; m++) rate += sRate[m];
                int t = ii*(n_inner+1) + jj + 1;
                outR[(size_t)b*nt + t] = rate;
                float trfull = s*s*trc;
                outC[(size_t)b*nt + t] = 1.0f/(2.0f*xi0*xi0*trfull + 1e-12f);
            }
            __syncthreads();
        } // jj

        // ---- outer step ----
        // O1: project F
        #pragma unroll
        for (int rep = 0; rep < 4; rep++){
            int idx = tid + rep*256; int n = idx >> 4, j = idx & 15;
            cf f = sF[n*17+j];
            float mag = hypotf(f.x, f.y);
            sF[n*17+j] = (mag > 1e-12f) ? mkc(f.x/mag, f.y/mag) : mkc(0.f, 0.f);
        }
        __syncthreads();
        // O2: MF = Mm@F ; v_m = F^H h_m
        #pragma unroll
        for (int rep = 0; rep < 4; rep++){
            int idx = tid + rep*256; int n = idx >> 4, j = idx & 15;
            cf acc = mkc(0,0);
            for (int kk = 0; kk < 64; kk++) cmad(acc, sMm[n*65+kk], sF[kk*17+j]);
            sMF[n*17+j] = acc;
        }
        if (tid < 128){
            int m = tid >> 4, r = tid & 15;
            cf acc = mkc(0,0);
            for (int n = 0; n < 64; n++) cmadc(acc, sF[n*17+r], sH[m*65+n]);
            sVm[tid] = acc;
        }
        __syncthreads();
        // O3: FHMF (+trace) ; t2 = V @ v_m
        float ptr2;
        {
            int i = tid >> 4, j = tid & 15;
            cf acc = mkc(0,0);
            for (int n = 0; n < 64; n++) cmadc(acc, sF[n*17+i], sMF[n*17+j]);
            sFHMF[tid] = acc;
            cf v = sV[j*16+i];
            ptr2 = acc.x*v.x - acc.y*v.y;
        }
        if (tid < 128){
            int m = tid >> 4, r = tid & 15;
            cf acc = mkc(0,0);
            for (int q = 0; q < 16; q++) cmad(acc, sV[r*16+q], sVm[m*16+q]);
            sT2[tid] = acc;
        }
        float trW = blockReduceSum(ptr2, sRed, &sBcast, tid);
        // O4: per-m coefs
        if (tid < 8){
            int m = tid;
            float trm = 0.f; cf a = mkc(0,0);
            for (int r = 0; r < 16; r++){
                cf vm = sVm[m*16+r], t2 = sT2[m*16+r];
                trm += vm.x*t2.x + vm.y*t2.y;
                cmadc(a, vm, sW[r*8+m]);
            }
            float invd = 1.0f/(LN2F*(trm + 1.0f)*8.0f);
            sCoefC[m] = mkc(a.x*invd, a.y*invd);
        }
        __syncthreads();
        // O5: gW
        if (tid < 128){
            int i = tid >> 3, mm = tid & 7;
            cf acc = mkc(0,0);
            for (int j2 = 0; j2 < 16; j2++) cmad(acc, sFHMF[i*16+j2], sW[j2*8+mm]);
            float hinv = 0.5f / trW;
            cf g = mkc(acc.x*hinv, acc.y*hinv);
            cmad(g, sVm[mm*16+i], sCoefC[mm]);
            sRow[tid] = g;
        }
        __syncthreads();
        // O6: RMSProp W update
        if (tid < 128){
            cf g = sRow[tid];
            cf sw = sSW[tid];
            sw.x = BETA_*sw.x + OMB_*g.x;
            sw.y = BETA_*sw.y + OMB_*g.y;
            sSW[tid] = sw;
            cf d = csqrtf2(sw); d.x += EPS_;
            cf upd = cdiv(g, d);
            cf w = sW[tid];
            w.x = fmaf(ETAW_, upd.x, w.x);
            w.y = fmaf(ETAW_, upd.y, w.y);
            sW[tid] = w;
        }
        __syncthreads();
        // O7: FW, power -> s
        float part = 0.f;
        #pragma unroll
        for (int rep = 0; rep < 2; rep++){
            int idx = tid + rep*256; int n = idx >> 3, k = idx & 7;
            cf acc = mkc(0,0);
            for (int r = 0; r < 16; r++) cmad(acc, sF[n*17+r], sW[r*8+k]);
            sFW[idx] = acc;
            part += acc.x*acc.x + acc.y*acc.y;
        }
        float pw = blockReduceSum(part, sRed, &sBcast, tid);
        float s = sqrtf(Pt / pw);
        // O8: crb trace (pre-scale) ; T = conj(H)@F ; scale W
        float ptrc = 0.f;
        #pragma unroll
        for (int rep = 0; rep < 2; rep++){
            int idx = tid + rep*256; int n = idx >> 3, k = idx & 7;
            cf acc = mkc(0,0);
            for (int kk = 0; kk < 64; kk++) cmad(acc, sMm[n*65+kk], sFW[kk*8+k]);
            cf fw = sFW[idx];
            ptrc += fw.x*acc.x + fw.y*acc.y;
        }
        if (tid < 128){
            int m = tid >> 4, j = tid & 15;
            cf acc = mkc(0,0);
            for (int n = 0; n < 64; n++) cmadc(acc, sH[m*65+n], sF[n*17+j]);
            sU[tid] = acc;
            cf w = sW[tid];
            sW[tid] = mkc(w.x*s, w.y*s);
        }
        float trc = blockReduceSum(ptrc, sRed, &sBcast, tid);
        // O9: S = T @ W_scaled
        if (tid < 64){
            int m = tid >> 3, k = tid & 7;
            cf acc = mkc(0,0);
            for (int j2 = 0; j2 < 16; j2++) cmad(acc, sU[m*16+j2], sW[j2*8+k]);
            sS[tid] = acc;
        }
        __syncthreads();
        // O10: rates/crb at t=0
        if (tid < 8){
            int m = tid;
            float tot = 0.f, sig = 0.f;
            for (int k = 0; k < 8; k++){
                cf v = sS[m*8+k];
                float p = v.x*v.x + v.y*v.y;
                tot += p; if (k == m) sig = p;
            }
            sRate[m] = log2f(1.0f + sig/((tot - sig) + 1.0f));
        }
        __syncthreads();
        if (tid == 0){
            float rate = 0.f;
            for (int m = 0; m < 8; m++) rate += sRate[m];
            int t = ii*(n_inner+1);
            outR[(size_t)b*nt + t] = rate;
            float trfull = s*s*trc;
            outC[(size_t)b*nt + t] = 1.0f/(2.0f*xi0*xi0*trfull + 1e-12f);
        }
        __syncthreads();
    } // ii

    // ---- write final F, W ----
    if (cplx){
        #pragma unroll
        for (int rep = 0; rep < 4; rep++){
            int idx = tid + rep*256; int n = idx >> 4, j = idx & 15;
            cf f = sF[n*17+j];
            size_t o = ((size_t)b*1024 + idx)*2;
            outF[o]   = f.x;
            outF[o+1] = f.y;
        }
        if (tid < 128){
            cf w = sW[tid];
            size_t o = ((size_t)b*128 + tid)*2;
            outW[o]   = w.x;
            outW[o+1] = w.y;
        }
    } else {
        #pragma unroll
        for (int rep = 0; rep < 4; rep++){
            int idx = tid + rep*256; int n = idx >> 4, j = idx & 15;
            outF[(size_t)b*1024 + idx] = sF[n*17+j].x;
        }
        if (tid < 128)
            outW[(size_t)b*128 + tid] = sW[tid].x;
    }
}

extern "C" void kernel_launch(void* const* d_in, const int* in_sizes, int n_in,
                              void* d_out, int out_size, void* d_ws, size_t ws_size,
                              hipStream_t stream)
{
    (void)n_in;
    int B = in_sizes[0] / 512;   // A*B*Mu*N / (8*64)

    // Infer output layout for complex64 F/W: 2 floats/elem (interleaved) or 1 (real-only).
    // interleaved: out_size = 2*B*nt + 2304*B ; real-only: out_size = 2*B*nt + 1152*B
    long S = (long)out_size;
    long numI = S - 2304L*B;
    long numR = S - 1152L*B;
    bool okI = (numI > 0) && (numI % (2L*B) == 0) && (numI/(2L*B) >= 1) && (numI/(2L*B) <= 256);
    bool okR = (numR > 0) && (numR % (2L*B) == 0) && (numR/(2L*B) >= 1) && (numR/(2L*B) <= 256);
    int cplx = okI ? 1 : (okR ? 0 : 1);

    const float* Ar = (const float*)d_in[6];
    const float* Ai = (const float*)d_in[7];
    const float* Rr = (const float*)d_in[8];
    const float* Ri = (const float*)d_in[9];

    cf* Mm = nullptr;
    if (d_ws != nullptr && ws_size >= 65536){
        Mm = (cf*)d_ws;
        pga_prep<<<1, 256, 0, stream>>>(Ar, Ai, Rr, Ri, Mm);
    }

    pga_main<<<B, 256, 0, stream>>>(
        (const float*)d_in[0], (const float*)d_in[1],
        (const float*)d_in[2], (const float*)d_in[3],
        (const float*)d_in[4], (const float*)d_in[5],
        Ar, Ai, Rr, Ri,
        Mm,
        (const float*)d_in[10],
        (const int*)d_in[11], (const int*)d_in[12], (const int*)d_in[13],
        (float*)d_out, B, cplx);
}

// Round 3
// 1316.617 us; speedup vs baseline: 1.3138x; 1.3138x over previous
//
#include <hip/hip_runtime.h>
#include <math.h>

// ---------------- complex helpers (float2 = re,im) ----------------
typedef float2 cf;

__device__ __forceinline__ cf mkc(float x, float y){ return make_float2(x,y); }

// acc += a*b
__device__ __forceinline__ void cmad(cf& acc, cf a, cf b){
    acc.x = fmaf(a.x, b.x, fmaf(-a.y, b.y, acc.x));
    acc.y = fmaf(a.x, b.y, fmaf( a.y, b.x, acc.y));
}
// acc += conj(a)*b
__device__ __forceinline__ void cmadc(cf& acc, cf a, cf b){
    acc.x = fmaf(a.x, b.x, fmaf( a.y, b.y, acc.x));
    acc.y = fmaf(a.x, b.y, fmaf(-a.y, b.x, acc.y));
}
// acc += a*conj(b)
__device__ __forceinline__ void cmad_bc(cf& acc, cf a, cf b){
    acc.x = fmaf(a.x, b.x, fmaf( a.y, b.y, acc.x));
    acc.y = fmaf(a.y, b.x, fmaf(-a.x, b.y, acc.y));
}
// principal complex sqrt (numpy branch conventions)
__device__ __forceinline__ cf csqrtf2(cf z){
    float x = z.x, y = z.y;
    float r = hypotf(x, y);
    if (r == 0.0f) return mkc(0.f, 0.f);
    if (x >= 0.0f){
        float t = sqrtf(0.5f*(r + x));
        return mkc(t, 0.5f*y/t);
    } else {
        float t = sqrtf(0.5f*(r - x));
        return mkc(0.5f*fabsf(y)/t, copysignf(t, y));
    }
}
// a / b
__device__ __forceinline__ cf cdiv(cf a, cf b){
    float inv = 1.0f/(b.x*b.x + b.y*b.y);
    return mkc((a.x*b.x + a.y*b.y)*inv, (a.y*b.x - a.x*b.y)*inv);
}

#define LN2F  0.69314718055994530942f
#define BETA_ 0.9f
#define OMB_  0.1f
#define EPS_  1e-8f
#define ETAF_ 0.01f
#define ETAW_ 0.01f

#define MM_S 66   /* sMm row stride (cf) — even: 16B-aligned rows */
#define F_S  18   /* sF / sMF row stride */
#define H_S  66   /* sH row stride */

__device__ __forceinline__ float readScalarF(const int* p){
    int iv = *p;
    if (iv >= 0 && iv < 1000000) return (float)iv;
    return __int_as_float(iv);
}
__device__ __forceinline__ int readScalarI(const int* p){
    int iv = *p;
    if (iv >= 0 && iv < 1000000) return iv;
    return (int)(__int_as_float(iv) + 0.5f);
}

// single-barrier block reduce; caller must rotate `slot` (4 floats) between
// back-to-back calls that have no other barrier in between
__device__ __forceinline__ float blockReduceSum(float v, float* slot, int tid){
    #pragma unroll
    for (int o = 32; o > 0; o >>= 1) v += __shfl_down(v, o, 64);
    if ((tid & 63) == 0) slot[tid >> 6] = v;
    __syncthreads();
    return slot[0] + slot[1] + slot[2] + slot[3];
}

// MF = Mm @ F  (64x16 out; thread j=tid&15 fixed, 4 rows; F columns cached)
__device__ __forceinline__ void computeMF(const cf* sMm, const cf* sF, cf* sMF, int tid){
    int j = tid & 15, nb = tid >> 4;
    cf a0=mkc(0,0), a1=mkc(0,0), a2=mkc(0,0), a3=mkc(0,0);
    for (int kkb = 0; kkb < 4; kkb++){
        cf f[16];
        #pragma unroll
        for (int q = 0; q < 16; q++) f[q] = sF[(kkb*16+q)*F_S + j];
        const cf* m0 = sMm + (nb    )*MM_S + kkb*16;
        const cf* m1 = sMm + (nb+16 )*MM_S + kkb*16;
        const cf* m2 = sMm + (nb+32 )*MM_S + kkb*16;
        const cf* m3 = sMm + (nb+48 )*MM_S + kkb*16;
        #pragma unroll
        for (int q = 0; q < 16; q++){
            cmad(a0, m0[q], f[q]);
            cmad(a1, m1[q], f[q]);
            cmad(a2, m2[q], f[q]);
            cmad(a3, m3[q], f[q]);
        }
    }
    sMF[(nb   )*F_S+j]=a0; sMF[(nb+16)*F_S+j]=a1;
    sMF[(nb+32)*F_S+j]=a2; sMF[(nb+48)*F_S+j]=a3;
}

// FW = F@W (into sFW), returns |FW|^2 partial
__device__ __forceinline__ float fwPartial(const cf* sF, const cf* sW, cf* sFW, int tid){
    int k = tid & 7, nb = tid >> 3;
    cf wcol[16];
    #pragma unroll
    for (int r = 0; r < 16; r++) wcol[r] = sW[r*8+k];
    float part = 0.f;
    #pragma unroll
    for (int rep = 0; rep < 2; rep++){
        int n = nb + rep*32;
        cf acc = mkc(0,0);
        #pragma unroll
        for (int r = 0; r < 16; r++) cmad(acc, sF[n*F_S+r], wcol[r]);
        sFW[n*8+k] = acc;
        part += acc.x*acc.x + acc.y*acc.y;
    }
    return part;
}

// partial of Re tr(FW^H Mm FW)
__device__ __forceinline__ float trcPartial(const cf* sMm, const cf* sFW, int tid){
    int k = tid & 7, nb = tid >> 3;
    cf y0 = mkc(0,0), y1 = mkc(0,0);
    for (int kkb = 0; kkb < 4; kkb++){
        cf fw[16];
        #pragma unroll
        for (int q = 0; q < 16; q++) fw[q] = sFW[(kkb*16+q)*8 + k];
        const cf* m0 = sMm + (nb   )*MM_S + kkb*16;
        const cf* m1 = sMm + (nb+32)*MM_S + kkb*16;
        #pragma unroll
        for (int q = 0; q < 16; q++){ cmad(y0, m0[q], fw[q]); cmad(y1, m1[q], fw[q]); }
    }
    cf a = sFW[nb*8+k], b2 = sFW[(nb+32)*8+k];
    return a.x*y0.x + a.y*y0.y + b2.x*y1.x + b2.y*y1.y;
}

// u[m,j] = sum_n conj(H[m,n]) F[n,j]
__device__ __forceinline__ cf uCompute(const cf* sH, const cf* sF, int m, int j){
    cf acc = mkc(0,0);
    for (int n = 0; n < 64; n++) cmadc(acc, sH[m*H_S+n], sF[n*F_S+j]);
    return acc;
}

// rates + crb write (wave 0 only); sU must already reflect final scaled state
__device__ __forceinline__ void ratesWrite(const cf* sU, const cf* sW, float trfull, float xi0,
                                           float* outR, float* outC, size_t base, int t, int tid){
    if (tid < 64){
        int m = tid >> 3, k = tid & 7;
        cf acc = mkc(0,0);
        #pragma unroll
        for (int j = 0; j < 16; j++) cmad(acc, sU[m*17+j], sW[j*8+k]);
        float p = acc.x*acc.x + acc.y*acc.y;
        float tot = p;
        #pragma unroll
        for (int mask = 4; mask >= 1; mask >>= 1) tot += __shfl_xor(tot, mask, 8);
        float sig = __shfl(p, 9*m, 64);
        float rate = log2f(1.0f + sig/((tot - sig) + 1.0f));
        float val = (k == 0) ? rate : 0.0f;
        #pragma unroll
        for (int mask = 32; mask >= 1; mask >>= 1) val += __shfl_xor(val, mask, 64);
        if (tid == 0){
            outR[base + t] = val;
            outC[base + t] = 1.0f/(2.0f*xi0*xi0*trfull + 1e-12f);
        }
    }
}

// ---------------- optional prep: Mm = A_dot^H @ R_N_inv @ A_dot (64x64) -> ws ----------------
__global__ __launch_bounds__(256) void pga_prep(
    const float* __restrict__ Ar, const float* __restrict__ Ai,
    const float* __restrict__ Rr, const float* __restrict__ Ri,
    cf* __restrict__ Mm)
{
    __shared__ cf sA[4096];
    __shared__ cf Tc[512];
    int tid = threadIdx.x;
    for (int idx = tid; idx < 4096; idx += 256)
        sA[idx] = mkc(Ar[idx], Ai[idx]);
    __syncthreads();
    for (int jb = 0; jb < 8; jb++){
        int j0 = jb*8;
        #pragma unroll
        for (int rep = 0; rep < 2; rep++){
            int idx = tid + rep*256;
            int p = idx >> 3, jc = idx & 7;
            cf acc = mkc(0,0);
            for (int q = 0; q < 64; q++){
                cf rv = mkc(Rr[p*64+q], Ri[p*64+q]);
                cmad(acc, rv, sA[q*64 + j0 + jc]);
            }
            Tc[idx] = acc;
        }
        __syncthreads();
        #pragma unroll
        for (int rep = 0; rep < 2; rep++){
            int idx = tid + rep*256;
            int i = idx >> 3, jc = idx & 7;
            cf acc = mkc(0,0);
            for (int p = 0; p < 64; p++)
                cmadc(acc, sA[p*64+i], Tc[p*8+jc]);
            Mm[i*64 + j0 + jc] = acc;
        }
        __syncthreads();
    }
}

// ---------------- main kernel ----------------
// Mu=8, N=64, R=16. LDS pool 70656 B -> 2 blocks/CU.
__global__ __launch_bounds__(256) void pga_main(
    const float* __restrict__ Hre, const float* __restrict__ Him,
    const float* __restrict__ F0re, const float* __restrict__ F0im,
    const float* __restrict__ W0re, const float* __restrict__ W0im,
    const float* __restrict__ Ar, const float* __restrict__ Ai,
    const float* __restrict__ Rr, const float* __restrict__ Ri,
    const cf* __restrict__ MmGlobal,
    const float* __restrict__ xi0p,
    const int* __restrict__ Ptp, const int* __restrict__ noutp, const int* __restrict__ ninnp,
    float* __restrict__ out, int B, int cplx)
{
    const int tid = threadIdx.x;
    const int b = blockIdx.x;

    __shared__ __align__(16) char sPool[70656];
    __shared__ float sRed[12];

    cf* sMm   = (cf*)(sPool + 0);       // 64 x MM_S      (33792 B)
    cf* sF    = (cf*)(sPool + 33792);   // 64 x F_S       ( 9216 B)
    cf* sMF   = (cf*)(sPool + 43008);   // 64 x F_S       ( 9216 B)
    cf* sH    = (cf*)(sPool + 52224);   // 8 x H_S        ( 4224 B)
    cf* sW    = (cf*)(sPool + 56448);   // [r*8+m]        ( 1024 B)
    cf* sV    = (cf*)(sPool + 57472);   // [i*16+j]       ( 2048 B)
    cf* sU    = (cf*)(sPool + 59520);   // [m*17+j]       ( 1088 B)
    cf* sRow  = (cf*)(sPool + 60608);   // [m*16+j]       ( 1024 B)
    cf* sVm   = (cf*)(sPool + 61632);   // [m*17+r]       ( 1088 B)
    cf* sFHMF = (cf*)(sPool + 62720);   // [i*17+j]       ( 2176 B)
    cf* sFW   = (cf*)(sPool + 64896);   // [n*8+k]        ( 4096 B)
    cf* sCoefC= (cf*)(sPool + 68992);   // [8]            (   64 B)

    const float Pt    = readScalarF(Ptp);
    const int n_outer = readScalarI(noutp);
    const int n_inner = readScalarI(ninnp);
    const float xi0   = xi0p[0];
    const int nt = n_outer * (n_inner + 1);

    float* outR = out;
    float* outC = out + (size_t)B * nt;
    float* outF = out + (size_t)2 * B * nt;
    float* outW = outF + (cplx ? (size_t)B * 2048 : (size_t)B * 1024);

    // ---- Mm into LDS ----
    if (MmGlobal){
        for (int idx = tid; idx < 4096; idx += 256){
            int r = idx >> 6, c = idx & 63;
            sMm[r*MM_S+c] = MmGlobal[idx];
        }
    } else {
        cf* sA = (cf*)(sPool + 33792);   // overlay (32768 B)
        cf* Tc = (cf*)(sPool + 66560);   // overlay ( 4096 B)
        for (int idx = tid; idx < 4096; idx += 256)
            sA[idx] = mkc(Ar[idx], Ai[idx]);
        __syncthreads();
        for (int jb = 0; jb < 8; jb++){
            int j0 = jb*8;
            #pragma unroll
            for (int rep = 0; rep < 2; rep++){
                int idx = tid + rep*256;
                int p = idx >> 3, jc = idx & 7;
                cf acc = mkc(0,0);
                for (int q = 0; q < 64; q++){
                    cf rv = mkc(Rr[p*64+q], Ri[p*64+q]);
                    cmad(acc, rv, sA[q*64 + j0 + jc]);
                }
                Tc[idx] = acc;
            }
            __syncthreads();
            #pragma unroll
            for (int rep = 0; rep < 2; rep++){
                int idx = tid + rep*256;
                int i2 = idx >> 3, jc = idx & 7;
                cf acc = mkc(0,0);
                for (int p = 0; p < 64; p++)
                    cmadc(acc, sA[p*64+i2], Tc[p*8+jc]);
                sMm[i2*MM_S + j0 + jc] = acc;
            }
            __syncthreads();
        }
    }

    // ---- load H, F (projected), W; RMSProp state in registers ----
    cf fsf[4]; cf ssw = mkc(0.f, 0.f);
    {
        const float* hr = Hre + (size_t)b*512;
        const float* hi = Him + (size_t)b*512;
        for (int idx = tid; idx < 512; idx += 256){
            int m = idx >> 6, n = idx & 63;
            sH[m*H_S+n] = mkc(hr[idx], hi[idx]);
        }
        const float* fr = F0re + (size_t)b*1024;
        const float* fi = F0im + (size_t)b*1024;
        for (int idx = tid; idx < 1024; idx += 256){
            int n = idx >> 4, r = idx & 15;
            float re = fr[idx], im = fi[idx];
            float mag = hypotf(re, im);
            sF[n*F_S+r] = (mag > 1e-12f) ? mkc(re/mag, im/mag) : mkc(0.f, 0.f);
        }
        if (tid < 128)
            sW[tid] = mkc(W0re[(size_t)b*128 + tid], W0im[(size_t)b*128 + tid]);
        #pragma unroll
        for (int rep = 0; rep < 4; rep++) fsf[rep] = mkc(0.f, 0.f);
    }
    __syncthreads();

    // ---- init: u = conj(H)@F ; W *= sqrt(Pt/|FW|^2) ----
    if (tid < 128){
        int m = tid >> 4, j = tid & 15;
        sU[m*17+j] = uCompute(sH, sF, m, j);
    }
    {
        float pw0 = blockReduceSum(fwPartial(sF, sW, sFW, tid), sRed+0, tid);
        float s0 = sqrtf(Pt / pw0);
        if (tid < 128){ cf w = sW[tid]; sW[tid] = mkc(w.x*s0, w.y*s0); }
    }
    __syncthreads();

    for (int ii = 0; ii < n_outer; ii++){
        // V = W W^H
        {
            int i = tid >> 4, j = tid & 15;
            cf acc = mkc(0,0);
            #pragma unroll
            for (int k = 0; k < 8; k++) cmad_bc(acc, sW[i*8+k], sW[j*8+k]);
            sV[tid] = acc;
        }
        __syncthreads();

        for (int jj = 0; jj < n_inner; jj++){
            // A: MF = Mm@F
            computeMF(sMm, sF, sMF, tid);
            __syncthreads();

            // B: G = MF@V (regs) + tr partial ; t2/coef/row via shuffles (tid<128)
            float ptr_;
            cf G0, G1, G2, G3;
            {
                int j = tid & 15, nb = tid >> 4;
                cf vcol[16];
                #pragma unroll
                for (int r = 0; r < 16; r++) vcol[r] = sV[r*16+j];
                G0 = G1 = G2 = G3 = mkc(0,0);
                #pragma unroll
                for (int r = 0; r < 16; r++){
                    cmad(G0, sMF[(nb   )*F_S+r], vcol[r]);
                    cmad(G1, sMF[(nb+16)*F_S+r], vcol[r]);
                    cmad(G2, sMF[(nb+32)*F_S+r], vcol[r]);
                    cmad(G3, sMF[(nb+48)*F_S+r], vcol[r]);
                }
                cf f0 = sF[(nb   )*F_S+j], f1 = sF[(nb+16)*F_S+j];
                cf f2 = sF[(nb+32)*F_S+j], f3 = sF[(nb+48)*F_S+j];
                ptr_ = f0.x*G0.x + f0.y*G0.y + f1.x*G1.x + f1.y*G1.y
                     + f2.x*G2.x + f2.y*G2.y + f3.x*G3.x + f3.y*G3.y;
            }
            if (tid < 128){
                int m = tid >> 4, j = tid & 15;
                cf u = sU[m*17+j];
                cf t2 = mkc(0,0);
                #pragma unroll
                for (int r = 0; r < 16; r++) cmad(t2, sU[m*17+r], sV[r*16+j]);
                float q = t2.x*u.x + t2.y*u.y;              // Re(t2*conj(u))
                cf c = mkc(0,0); cmad(c, u, sW[j*8+m]);     // u_j * W[j,m]
                #pragma unroll
                for (int mask = 8; mask >= 1; mask >>= 1){
                    q   += __shfl_xor(q,   mask, 16);
                    c.x += __shfl_xor(c.x, mask, 16);
                    c.y += __shfl_xor(c.y, mask, 16);
                }
                float qf2 = q - (c.x*c.x + c.y*c.y);
                float inv1 = 1.0f/(LN2F*(q   + 1.0f) + 1e-4f);
                float inv2 = 1.0f/(LN2F*(qf2 + 1.0f) + 1e-4f);
                float a = inv1 - inv2;
                cf cc = mkc(c.x*inv2, c.y*inv2);
                cf row = mkc(t2.x*a, t2.y*a);
                cmad_bc(row, cc, sW[j*8+m]);                // + (c/d2)*conj(W[j,m])
                sRow[tid] = row;                             // [m*16+j] == tid
            }
            float tr = blockReduceSum(ptr_, sRed+0, tid);

            // D: gF = 0.5*G/tr + sum_m H[m,n]*row ; RMSProp (reg state) ; F update
            {
                float hinv = 0.5f / tr;
                int j = tid & 15, nb = tid >> 4;
                cf Gs[4] = {G0, G1, G2, G3};
                #pragma unroll
                for (int rep = 0; rep < 4; rep++){
                    int n = nb + rep*16;
                    cf g = mkc(Gs[rep].x*hinv, Gs[rep].y*hinv);
                    #pragma unroll
                    for (int m = 0; m < 8; m++) cmad(g, sH[m*H_S+n], sRow[m*16+j]);
                    cf sf = fsf[rep];
                    sf.x = BETA_*sf.x + OMB_*g.x;
                    sf.y = BETA_*sf.y + OMB_*g.y;
                    fsf[rep] = sf;
                    cf d = csqrtf2(sf); d.x += EPS_;
                    cf upd = cdiv(g, d);
                    cf f = sF[n*F_S+j];
                    f.x = fmaf(ETAF_, upd.x, f.x);
                    f.y = fmaf(ETAF_, upd.y, f.y);
                    sF[n*F_S+j] = f;
                }
            }
            __syncthreads();

            // E: FW + power -> s
            float pw = blockReduceSum(fwPartial(sF, sW, sFW, tid), sRed+4, tid);
            float s = sqrtf(Pt / pw);

            // F: trc partial ; u refresh (unscaled)
            float ptrc = trcPartial(sMm, sFW, tid);
            if (tid < 128){
                int m = tid >> 4, j = tid & 15;
                sU[m*17+j] = uCompute(sH, sF, m, j);
            }
            float trc = blockReduceSum(ptrc, sRed+8, tid);

            // G: scale F and u by s
            {
                int j = tid & 15, nb = tid >> 4;
                #pragma unroll
                for (int rep = 0; rep < 4; rep++){
                    int n = nb + rep*16;
                    cf f = sF[n*F_S+j];
                    sF[n*F_S+j] = mkc(f.x*s, f.y*s);
                }
            }
            if (tid < 128){
                int m = tid >> 4, j = tid & 15;
                cf u = sU[m*17+j];
                sU[m*17+j] = mkc(u.x*s, u.y*s);
            }
            __syncthreads();

            // H: rates/crb tracking
            ratesWrite(sU, sW, s*s*trc, xi0, outR, outC, (size_t)b*nt,
                       ii*(n_inner+1) + jj + 1, tid);
        } // jj

        // ---- outer step ----
        // O1: project F
        {
            int j = tid & 15, nb = tid >> 4;
            #pragma unroll
            for (int rep = 0; rep < 4; rep++){
                int n = nb + rep*16;
                cf f = sF[n*F_S+j];
                float mag = hypotf(f.x, f.y);
                sF[n*F_S+j] = (mag > 1e-12f) ? mkc(f.x/mag, f.y/mag) : mkc(0.f, 0.f);
            }
        }
        __syncthreads();
        // O2: MF = Mm@F ; Vm[m,r] = F^H h_m
        computeMF(sMm, sF, sMF, tid);
        if (tid < 128){
            int m = tid >> 4, r = tid & 15;
            cf acc = mkc(0,0);
            for (int n = 0; n < 64; n++) cmadc(acc, sF[n*F_S+r], sH[m*H_S+n]);
            sVm[m*17+r] = acc;
        }
        __syncthreads();
        // O3: FHMF + tr partial ; coef via shuffles
        float ptr2;
        {
            int i = tid >> 4, j = tid & 15;
            cf acc = mkc(0,0);
            for (int n = 0; n < 64; n++) cmadc(acc, sF[n*F_S+i], sMF[n*F_S+j]);
            sFHMF[i*17+j] = acc;
            cf v = sV[j*16+i];
            ptr2 = acc.x*v.x - acc.y*v.y;
        }
        if (tid < 128){
            int m = tid >> 4, r = tid & 15;
            cf vm = sVm[m*17+r];
            cf t2 = mkc(0,0);
            #pragma unroll
            for (int q = 0; q < 16; q++) cmadc(t2, sV[q*16+r], sVm[m*17+q]); // V[r,q]=conj(V[q,r])
            float trm = vm.x*t2.x + vm.y*t2.y;
            cf a = mkc(0,0); cmadc(a, vm, sW[r*8+m]);
            #pragma unroll
            for (int mask = 8; mask >= 1; mask >>= 1){
                trm += __shfl_xor(trm, mask, 16);
                a.x += __shfl_xor(a.x, mask, 16);
                a.y += __shfl_xor(a.y, mask, 16);
            }
            if (r == 0){
                float invd = 1.0f/(LN2F*(trm + 1.0f)*8.0f);
                sCoefC[m] = mkc(a.x*invd, a.y*invd);
            }
        }
        float trW = blockReduceSum(ptr2, sRed+0, tid);
        // O5a: gW in regs
        cf gw = mkc(0,0);
        if (tid < 128){
            int i = tid >> 3, mm = tid & 7;
            cf acc = mkc(0,0);
            #pragma unroll
            for (int j2 = 0; j2 < 16; j2++) cmad(acc, sFHMF[i*17+j2], sW[j2*8+mm]);
            float hinv = 0.5f / trW;
            gw = mkc(acc.x*hinv, acc.y*hinv);
            cmad(gw, sVm[mm*17+i], sCoefC[mm]);
        }
        __syncthreads();
        // O5b: RMSProp W update (reg state)
        if (tid < 128){
            cf sw = ssw;
            sw.x = BETA_*sw.x + OMB_*gw.x;
            sw.y = BETA_*sw.y + OMB_*gw.y;
            ssw = sw;
            cf d = csqrtf2(sw); d.x += EPS_;
            cf upd = cdiv(gw, d);
            cf w = sW[tid];
            w.x = fmaf(ETAW_, upd.x, w.x);
            w.y = fmaf(ETAW_, upd.y, w.y);
            sW[tid] = w;
        }
        __syncthreads();
        // O7: FW + power -> s
        float pw2 = blockReduceSum(fwPartial(sF, sW, sFW, tid), sRed+4, tid);
        float s2 = sqrtf(Pt / pw2);
        // O8: trc partial ; u refresh (F unscaled in outer -> final)
        float ptrc2 = trcPartial(sMm, sFW, tid);
        if (tid < 128){
            int m = tid >> 4, j = tid & 15;
            sU[m*17+j] = uCompute(sH, sF, m, j);
        }
        float trc2 = blockReduceSum(ptrc2, sRed+8, tid);
        // O9: scale W
        if (tid < 128){
            cf w = sW[tid];
            sW[tid] = mkc(w.x*s2, w.y*s2);
        }
        __syncthreads();
        // O10: rates/crb at slot 0
        ratesWrite(sU, sW, s2*s2*trc2, xi0, outR, outC, (size_t)b*nt,
                   ii*(n_inner+1), tid);
        __syncthreads();
    } // ii

    // ---- write final F, W ----
    if (cplx){
        int j = tid & 15, nb = tid >> 4;
        #pragma unroll
        for (int rep = 0; rep < 4; rep++){
            int n = nb + rep*16;
            cf f = sF[n*F_S+j];
            size_t o = ((size_t)b*1024 + (size_t)(tid + rep*256))*2;
            outF[o]   = f.x;
            outF[o+1] = f.y;
        }
        if (tid < 128){
            cf w = sW[tid];
            size_t o = ((size_t)b*128 + tid)*2;
            outW[o]   = w.x;
            outW[o+1] = w.y;
        }
    } else {
        int j = tid & 15, nb = tid >> 4;
        #pragma unroll
        for (int rep = 0; rep < 4; rep++){
            int n = nb + rep*16;
            outF[(size_t)b*1024 + (size_t)(tid + rep*256)] = sF[n*F_S+j].x;
        }
        if (tid < 128)
            outW[(size_t)b*128 + tid] = sW[tid].x;
    }
}

extern "C" void kernel_launch(void* const* d_in, const int* in_sizes, int n_in,
                              void* d_out, int out_size, void* d_ws, size_t ws_size,
                              hipStream_t stream)
{
    (void)n_in;
    int B = in_sizes[0] / 512;   // A*B*Mu*N / (8*64)

    // Infer output layout for complex64 F/W: 2 floats/elem (interleaved) or 1 (real-only).
    long S = (long)out_size;
    long numI = S - 2304L*B;
    long numR = S - 1152L*B;
    bool okI = (numI > 0) && (numI % (2L*B) == 0) && (numI/(2L*B) >= 1) && (numI/(2L*B) <= 256);
    bool okR = (numR > 0) && (numR % (2L*B) == 0) && (numR/(2L*B) >= 1) && (numR/(2L*B) <= 256);
    int cplx = okI ? 1 : (okR ? 0 : 1);

    const float* Ar = (const float*)d_in[6];
    const float* Ai = (const float*)d_in[7];
    const float* Rr = (const float*)d_in[8];
    const float* Ri = (const float*)d_in[9];

    cf* Mm = nullptr;
    if (d_ws != nullptr && ws_size >= 65536){
        Mm = (cf*)d_ws;
        pga_prep<<<1, 256, 0, stream>>>(Ar, Ai, Rr, Ri, Mm);
    }

    pga_main<<<B, 256, 0, stream>>>(
        (const float*)d_in[0], (const float*)d_in[1],
        (const float*)d_in[2], (const float*)d_in[3],
        (const float*)d_in[4], (const float*)d_in[5],
        Ar, Ai, Rr, Ri,
        Mm,
        (const float*)d_in[10],
        (const int*)d_in[11], (const int*)d_in[12], (const int*)d_in[13],
        (float*)d_out, B, cplx);
}

// Round 4
// 1070.709 us; speedup vs baseline: 1.6156x; 1.2297x over previous
//
#include <hip/hip_runtime.h>
#include <math.h>

// ---------------- complex helpers (float2 = re,im) ----------------
typedef float2 cf;

__device__ __forceinline__ cf mkc(float x, float y){ return make_float2(x,y); }
__device__ __forceinline__ cf lo4(float4 v){ return mkc(v.x, v.y); }
__device__ __forceinline__ cf hi4(float4 v){ return mkc(v.z, v.w); }

// acc += a*b
__device__ __forceinline__ void cmad(cf& acc, cf a, cf b){
    acc.x = fmaf(a.x, b.x, fmaf(-a.y, b.y, acc.x));
    acc.y = fmaf(a.x, b.y, fmaf( a.y, b.x, acc.y));
}
// acc += conj(a)*b
__device__ __forceinline__ void cmadc(cf& acc, cf a, cf b){
    acc.x = fmaf(a.x, b.x, fmaf( a.y, b.y, acc.x));
    acc.y = fmaf(a.x, b.y, fmaf(-a.y, b.x, acc.y));
}
// acc += a*conj(b)
__device__ __forceinline__ void cmad_bc(cf& acc, cf a, cf b){
    acc.x = fmaf(a.x, b.x, fmaf( a.y, b.y, acc.x));
    acc.y = fmaf(a.y, b.x, fmaf(-a.x, b.y, acc.y));
}
// acc += conj(a)*conj(b)
__device__ __forceinline__ void cmad_cc(cf& acc, cf a, cf b){
    acc.x = fmaf(a.x, b.x, fmaf(-a.y, b.y, acc.x));
    acc.y = fmaf(-a.x, b.y, fmaf(-a.y, b.x, acc.y));
}
// principal complex sqrt (numpy branch conventions)
__device__ __forceinline__ cf csqrtf2(cf z){
    float x = z.x, y = z.y;
    float r = hypotf(x, y);
    if (r == 0.0f) return mkc(0.f, 0.f);
    if (x >= 0.0f){
        float t = sqrtf(0.5f*(r + x));
        return mkc(t, 0.5f*y/t);
    } else {
        float t = sqrtf(0.5f*(r - x));
        return mkc(0.5f*fabsf(y)/t, copysignf(t, y));
    }
}
// a / b
__device__ __forceinline__ cf cdiv(cf a, cf b){
    float inv = 1.0f/(b.x*b.x + b.y*b.y);
    return mkc((a.x*b.x + a.y*b.y)*inv, (a.y*b.x - a.x*b.y)*inv);
}

#define LN2F  0.69314718055994530942f
#define BETA_ 0.9f
#define OMB_  0.1f
#define EPS_  1e-8f
#define ETAF_ 0.01f
#define ETAW_ 0.01f

#define MM_S 66   /* sMm row stride (cf) — 16B-aligned rows */
#define F_S  18   /* sF / sMF row stride */
#define FT_S 66   /* sFT row stride (16 rows x 64) */
#define H_S  66   /* sH row stride */
#define U_S  18   /* sU row stride */

__device__ __forceinline__ float readScalarF(const int* p){
    int iv = *p;
    if (iv >= 0 && iv < 1000000) return (float)iv;
    return __int_as_float(iv);
}
__device__ __forceinline__ int readScalarI(const int* p){
    int iv = *p;
    if (iv >= 0 && iv < 1000000) return iv;
    return (int)(__int_as_float(iv) + 0.5f);
}

// single-barrier block reduce; rotate `slot` between back-to-back calls
__device__ __forceinline__ float blockReduceSum(float v, float* slot, int tid){
    #pragma unroll
    for (int o = 32; o > 0; o >>= 1) v += __shfl_down(v, o, 64);
    if ((tid & 63) == 0) slot[tid >> 6] = v;
    __syncthreads();
    return slot[0] + slot[1] + slot[2] + slot[3];
}

// MF = Mm @ F via FT (row-contiguous b128 streams). thread (nb=tid>>4, j=tid&15), 4 rows.
__device__ __forceinline__ void computeMF_T(const cf* sMm, const cf* sFT, cf* sMF, int tid){
    int j = tid & 15, nb = tid >> 4;
    cf a0=mkc(0,0), a1=mkc(0,0), a2=mkc(0,0), a3=mkc(0,0);
    const float4* ftrow = (const float4*)(sFT + j*FT_S);
    #pragma unroll
    for (int kkb = 0; kkb < 4; kkb++){
        cf f[16];
        #pragma unroll
        for (int q = 0; q < 8; q++){
            float4 v = ftrow[kkb*8+q];
            f[2*q] = lo4(v); f[2*q+1] = hi4(v);
        }
        const float4* m0 = (const float4*)(sMm + (nb    )*MM_S + kkb*16);
        const float4* m1 = (const float4*)(sMm + (nb+16 )*MM_S + kkb*16);
        const float4* m2 = (const float4*)(sMm + (nb+32 )*MM_S + kkb*16);
        const float4* m3 = (const float4*)(sMm + (nb+48 )*MM_S + kkb*16);
        #pragma unroll
        for (int q = 0; q < 8; q++){
            float4 v0 = m0[q], v1 = m1[q], v2 = m2[q], v3 = m3[q];
            cmad(a0, lo4(v0), f[2*q]); cmad(a0, hi4(v0), f[2*q+1]);
            cmad(a1, lo4(v1), f[2*q]); cmad(a1, hi4(v1), f[2*q+1]);
            cmad(a2, lo4(v2), f[2*q]); cmad(a2, hi4(v2), f[2*q+1]);
            cmad(a3, lo4(v3), f[2*q]); cmad(a3, hi4(v3), f[2*q+1]);
        }
    }
    sMF[(nb   )*F_S+j]=a0; sMF[(nb+16)*F_S+j]=a1;
    sMF[(nb+32)*F_S+j]=a2; sMF[(nb+48)*F_S+j]=a3;
}

// u[m][j] = sum_n conj(H[m,n]) F[n,j], split-K over 256 threads, shuffle-combine
__device__ __forceinline__ void uRefresh(const cf* sH, const cf* sFT, cf* sU, int tid){
    int h = tid & 1, j = (tid >> 1) & 15, m = tid >> 5;
    const float4* hp = (const float4*)(sH  + m*H_S  + h*32);
    const float4* fp = (const float4*)(sFT + j*FT_S + h*32);
    cf acc = mkc(0,0);
    #pragma unroll
    for (int q = 0; q < 16; q++){
        float4 hv = hp[q], fv = fp[q];
        cmadc(acc, lo4(hv), lo4(fv));
        cmadc(acc, hi4(hv), hi4(fv));
    }
    acc.x += __shfl_xor(acc.x, 1, 64);
    acc.y += __shfl_xor(acc.y, 1, 64);
    if (h == 0) sU[m*U_S+j] = acc;
}

// FW = F@W (rows of sF as b128), returns |FW|^2 partial
__device__ __forceinline__ float fwPartial(const cf* sF, const cf* sW, cf* sFW, int tid){
    int k = tid & 7, nb = tid >> 3;
    cf wcol[16];
    #pragma unroll
    for (int r = 0; r < 16; r++) wcol[r] = sW[r*8+k];
    float part = 0.f;
    #pragma unroll
    for (int rep = 0; rep < 2; rep++){
        int n = nb + rep*32;
        const float4* fr = (const float4*)(sF + n*F_S);
        cf acc = mkc(0,0);
        #pragma unroll
        for (int q = 0; q < 8; q++){
            float4 v = fr[q];
            cmad(acc, lo4(v), wcol[2*q]); cmad(acc, hi4(v), wcol[2*q+1]);
        }
        sFW[n*8+k] = acc;
        part += acc.x*acc.x + acc.y*acc.y;
    }
    return part;
}

// trc partial via Y = MF@W:  sum Re(conj(FW) * (MF@W))
__device__ __forceinline__ float trcViaMF(const cf* sMF, const cf* sW, const cf* sFW, int tid){
    int k = tid & 7, nb = tid >> 3;
    cf wcol[16];
    #pragma unroll
    for (int r = 0; r < 16; r++) wcol[r] = sW[r*8+k];
    float ptrc = 0.f;
    #pragma unroll
    for (int rep = 0; rep < 2; rep++){
        int n = nb + rep*32;
        const float4* mr = (const float4*)(sMF + n*F_S);
        cf acc = mkc(0,0);
        #pragma unroll
        for (int q = 0; q < 8; q++){
            float4 v = mr[q];
            cmad(acc, lo4(v), wcol[2*q]); cmad(acc, hi4(v), wcol[2*q+1]);
        }
        cf fw = sFW[n*8+k];
        ptrc += fw.x*acc.x + fw.y*acc.y;
    }
    return ptrc;
}

// rates + crb write (wave 0 only); sU must reflect final scaled state
__device__ __forceinline__ void ratesWrite(const cf* sU, const cf* sW, float trfull, float xi0,
                                           float* outR, float* outC, size_t base, int t, int tid){
    if (tid < 64){
        int m = tid >> 3, k = tid & 7;
        cf acc = mkc(0,0);
        #pragma unroll
        for (int j = 0; j < 16; j++) cmad(acc, sU[m*U_S+j], sW[j*8+k]);
        float p = acc.x*acc.x + acc.y*acc.y;
        float tot = p;
        #pragma unroll
        for (int mask = 4; mask >= 1; mask >>= 1) tot += __shfl_xor(tot, mask, 8);
        float sig = __shfl(p, 9*m, 64);
        float rate = log2f(1.0f + sig/((tot - sig) + 1.0f));
        float val = (k == 0) ? rate : 0.0f;
        #pragma unroll
        for (int mask = 32; mask >= 1; mask >>= 1) val += __shfl_xor(val, mask, 64);
        if (tid == 0){
            outR[base + t] = val;
            outC[base + t] = 1.0f/(2.0f*xi0*xi0*trfull + 1e-12f);
        }
    }
}

// ---------------- optional prep: Mm = A_dot^H @ R_N_inv @ A_dot (64x64) -> ws ----------------
__global__ __launch_bounds__(256) void pga_prep(
    const float* __restrict__ Ar, const float* __restrict__ Ai,
    const float* __restrict__ Rr, const float* __restrict__ Ri,
    cf* __restrict__ Mm)
{
    __shared__ cf sA[4096];
    __shared__ cf Tc[512];
    int tid = threadIdx.x;
    for (int idx = tid; idx < 4096; idx += 256)
        sA[idx] = mkc(Ar[idx], Ai[idx]);
    __syncthreads();
    for (int jb = 0; jb < 8; jb++){
        int j0 = jb*8;
        #pragma unroll
        for (int rep = 0; rep < 2; rep++){
            int idx = tid + rep*256;
            int p = idx >> 3, jc = idx & 7;
            cf acc = mkc(0,0);
            for (int q = 0; q < 64; q++){
                cf rv = mkc(Rr[p*64+q], Ri[p*64+q]);
                cmad(acc, rv, sA[q*64 + j0 + jc]);
            }
            Tc[idx] = acc;
        }
        __syncthreads();
        #pragma unroll
        for (int rep = 0; rep < 2; rep++){
            int idx = tid + rep*256;
            int i = idx >> 3, jc = idx & 7;
            cf acc = mkc(0,0);
            for (int p = 0; p < 64; p++)
                cmadc(acc, sA[p*64+i], Tc[p*8+jc]);
            Mm[i*64 + j0 + jc] = acc;
        }
        __syncthreads();
    }
}

// ---------------- main kernel ----------------
// Mu=8, N=64, R=16. LDS pool 76480 B -> 2 blocks/CU.
__global__ __launch_bounds__(256) void pga_main(
    const float* __restrict__ Hre, const float* __restrict__ Him,
    const float* __restrict__ F0re, const float* __restrict__ F0im,
    const float* __restrict__ W0re, const float* __restrict__ W0im,
    const float* __restrict__ Ar, const float* __restrict__ Ai,
    const float* __restrict__ Rr, const float* __restrict__ Ri,
    const cf* __restrict__ MmGlobal,
    const float* __restrict__ xi0p,
    const int* __restrict__ Ptp, const int* __restrict__ noutp, const int* __restrict__ ninnp,
    float* __restrict__ out, int B, int cplx)
{
    const int tid = threadIdx.x;
    const int b = blockIdx.x;

    __shared__ __align__(16) char sPool[76480];
    __shared__ float sRed[12];

    cf* sMm   = (cf*)(sPool + 0);       // 64 x 66        (33792 B)
    cf* sF    = (cf*)(sPool + 33792);   // 64 x 18        ( 9216 B)
    cf* sMF   = (cf*)(sPool + 43008);   // 64 x 18        ( 9216 B)
    cf* sFT   = (cf*)(sPool + 52224);   // 16 x 66        ( 8448 B)
    cf* sH    = (cf*)(sPool + 60672);   // 8 x 66         ( 4224 B)
    cf* sW    = (cf*)(sPool + 64896);   // [r*8+m]        ( 1024 B)
    cf* sV    = (cf*)(sPool + 65920);   // [i*16+j]       ( 2048 B)
    cf* sU    = (cf*)(sPool + 67968);   // [m*18+j]       ( 1152 B)
    cf* sRow  = (cf*)(sPool + 69120);   // [m*16+j]       ( 1024 B)
    cf* sFHMF = (cf*)(sPool + 70144);   // [i*17+j]       ( 2176 B)
    cf* sFW   = (cf*)(sPool + 72320);   // [n*8+k]        ( 4096 B)
    cf* sCoefC= (cf*)(sPool + 76416);   // [8]            (   64 B)

    const float Pt    = readScalarF(Ptp);
    const int n_outer = readScalarI(noutp);
    const int n_inner = readScalarI(ninnp);
    const float xi0   = xi0p[0];
    const int nt = n_outer * (n_inner + 1);

    float* outR = out;
    float* outC = out + (size_t)B * nt;
    float* outF = out + (size_t)2 * B * nt;
    float* outW = outF + (cplx ? (size_t)B * 2048 : (size_t)B * 1024);

    // ---- Mm into LDS ----
    if (MmGlobal){
        for (int idx = tid; idx < 4096; idx += 256){
            int r = idx >> 6, c = idx & 63;
            sMm[r*MM_S+c] = MmGlobal[idx];
        }
    } else {
        cf* sA = (cf*)(sPool + 33792);   // overlay (32768 B)
        cf* Tc = (cf*)(sPool + 66560);   // overlay ( 4096 B)
        for (int idx = tid; idx < 4096; idx += 256)
            sA[idx] = mkc(Ar[idx], Ai[idx]);
        __syncthreads();
        for (int jb = 0; jb < 8; jb++){
            int j0 = jb*8;
            #pragma unroll
            for (int rep = 0; rep < 2; rep++){
                int idx = tid + rep*256;
                int p = idx >> 3, jc = idx & 7;
                cf acc = mkc(0,0);
                for (int q = 0; q < 64; q++){
                    cf rv = mkc(Rr[p*64+q], Ri[p*64+q]);
                    cmad(acc, rv, sA[q*64 + j0 + jc]);
                }
                Tc[idx] = acc;
            }
            __syncthreads();
            #pragma unroll
            for (int rep = 0; rep < 2; rep++){
                int idx = tid + rep*256;
                int i2 = idx >> 3, jc = idx & 7;
                cf acc = mkc(0,0);
                for (int p = 0; p < 64; p++)
                    cmadc(acc, sA[p*64+i2], Tc[p*8+jc]);
                sMm[i2*MM_S + j0 + jc] = acc;
            }
            __syncthreads();
        }
        __syncthreads();
    }

    // ---- load H, F (projected -> sF & sFT), W; RMSProp state in regs ----
    cf fsf[4]; cf ssw = mkc(0.f, 0.f);
    {
        const float* hr = Hre + (size_t)b*512;
        const float* hi = Him + (size_t)b*512;
        for (int idx = tid; idx < 512; idx += 256){
            int m = idx >> 6, n = idx & 63;
            sH[m*H_S+n] = mkc(hr[idx], hi[idx]);
        }
        const float* fr = F0re + (size_t)b*1024;
        const float* fi = F0im + (size_t)b*1024;
        for (int idx = tid; idx < 1024; idx += 256){
            int n = idx >> 4, r = idx & 15;
            float re = fr[idx], im = fi[idx];
            float mag = hypotf(re, im);
            cf f = (mag > 1e-12f) ? mkc(re/mag, im/mag) : mkc(0.f, 0.f);
            sF[n*F_S+r] = f;
            sFT[r*FT_S+n] = f;
        }
        if (tid < 128)
            sW[tid] = mkc(W0re[(size_t)b*128 + tid], W0im[(size_t)b*128 + tid]);
        #pragma unroll
        for (int rep = 0; rep < 4; rep++) fsf[rep] = mkc(0.f, 0.f);
    }
    __syncthreads();

    // ---- init: u, FW/power -> scale W ; MF ----
    uRefresh(sH, sFT, sU, tid);
    {
        float pw0 = blockReduceSum(fwPartial(sF, sW, sFW, tid), sRed+0, tid);
        float s0 = sqrtf(Pt / pw0);
        if (tid < 128){ cf w = sW[tid]; sW[tid] = mkc(w.x*s0, w.y*s0); }
    }
    computeMF_T(sMm, sFT, sMF, tid);
    __syncthreads();

    for (int ii = 0; ii < n_outer; ii++){
        // V = W W^H
        {
            int i = tid >> 4, j = tid & 15;
            cf acc = mkc(0,0);
            #pragma unroll
            for (int k = 0; k < 8; k++) cmad_bc(acc, sW[i*8+k], sW[j*8+k]);
            sV[tid] = acc;
        }
        __syncthreads();

        for (int jj = 0; jj < n_inner; jj++){
            const int j = tid & 15, nb = tid >> 4;
            // B: G = MF@V in regs + tr partial; coef/row phase (tid<128)
            float ptr_ = 0.f;
            cf G[4];
            cf vcol[16];
            {
                #pragma unroll
                for (int r = 0; r < 16; r++) vcol[r] = sV[r*16+j];
                #pragma unroll
                for (int rep = 0; rep < 4; rep++){
                    int n = nb + rep*16;
                    const float4* mr = (const float4*)(sMF + n*F_S);
                    cf acc = mkc(0,0);
                    #pragma unroll
                    for (int q = 0; q < 8; q++){
                        float4 v = mr[q];
                        cmad(acc, lo4(v), vcol[2*q]); cmad(acc, hi4(v), vcol[2*q+1]);
                    }
                    G[rep] = acc;
                    cf f = sF[n*F_S+j];
                    ptr_ += f.x*acc.x + f.y*acc.y;
                }
            }
            if (tid < 128){
                int m = tid >> 4;   // j as above
                const float4* up = (const float4*)(sU + m*U_S);
                cf t2 = mkc(0,0);
                #pragma unroll
                for (int q = 0; q < 8; q++){
                    float4 uv = up[q];
                    cmad(t2, lo4(uv), vcol[2*q]); cmad(t2, hi4(uv), vcol[2*q+1]);
                }
                cf u = sU[m*U_S+j];
                float qv = t2.x*u.x + t2.y*u.y;             // Re(t2*conj(u))
                cf c = mkc(0,0); cmad(c, u, sW[j*8+m]);
                #pragma unroll
                for (int mask = 8; mask >= 1; mask >>= 1){
                    qv  += __shfl_xor(qv,  mask, 16);
                    c.x += __shfl_xor(c.x, mask, 16);
                    c.y += __shfl_xor(c.y, mask, 16);
                }
                float qf2 = qv - (c.x*c.x + c.y*c.y);
                float inv1 = 1.0f/(LN2F*(qv  + 1.0f) + 1e-4f);
                float inv2 = 1.0f/(LN2F*(qf2 + 1.0f) + 1e-4f);
                float a = inv1 - inv2;
                cf cc = mkc(c.x*inv2, c.y*inv2);
                cf row = mkc(t2.x*a, t2.y*a);
                cmad_bc(row, cc, sW[j*8+m]);
                sRow[tid] = row;
            }
            float tr = blockReduceSum(ptr_, sRed+0, tid);   // barrier B1

            // D: gF + RMSProp + F update (writes sF, sFT)
            {
                float hinv = 0.5f / tr;
                cf rowj[8];
                #pragma unroll
                for (int m = 0; m < 8; m++) rowj[m] = sRow[m*16+j];
                #pragma unroll
                for (int rep = 0; rep < 4; rep++){
                    int n = nb + rep*16;
                    cf g = mkc(G[rep].x*hinv, G[rep].y*hinv);
                    #pragma unroll
                    for (int m = 0; m < 8; m++) cmad(g, sH[m*H_S+n], rowj[m]);
                    cf sf = fsf[rep];
                    sf.x = BETA_*sf.x + OMB_*g.x;
                    sf.y = BETA_*sf.y + OMB_*g.y;
                    fsf[rep] = sf;
                    cf d = csqrtf2(sf); d.x += EPS_;
                    cf upd = cdiv(g, d);
                    cf f = sF[n*F_S+j];
                    f.x = fmaf(ETAF_, upd.x, f.x);
                    f.y = fmaf(ETAF_, upd.y, f.y);
                    sF[n*F_S+j] = f;
                    sFT[j*FT_S+n] = f;
                }
            }
            __syncthreads();                                 // barrier B2

            // A': MF = Mm@F_new ; E: FW/power ; U: u refresh
            computeMF_T(sMm, sFT, sMF, tid);
            float part = fwPartial(sF, sW, sFW, tid);
            uRefresh(sH, sFT, sU, tid);
            float pw = blockReduceSum(part, sRed+4, tid);    // barrier B3
            float s = sqrtf(Pt / pw);

            // Y: trc via MF@W
            float ptrc = trcViaMF(sMF, sW, sFW, tid);
            float trc = blockReduceSum(ptrc, sRed+8, tid);   // barrier B4

            // S: scale sF, sFT, sMF, sU by s
            {
                #pragma unroll
                for (int rep = 0; rep < 4; rep++){
                    int n = nb + rep*16;
                    cf f = sF[n*F_S+j];  sF[n*F_S+j]  = mkc(f.x*s, f.y*s);
                    cf ft= sFT[j*FT_S+n];sFT[j*FT_S+n]= mkc(ft.x*s, ft.y*s);
                    cf mf= sMF[n*F_S+j]; sMF[n*F_S+j] = mkc(mf.x*s, mf.y*s);
                }
                if (tid < 128){
                    int m = tid >> 4;
                    cf u = sU[m*U_S+j];
                    sU[m*U_S+j] = mkc(u.x*s, u.y*s);
                }
            }
            __syncthreads();                                 // barrier B5

            // R: tracking
            ratesWrite(sU, sW, s*s*trc, xi0, outR, outC, (size_t)b*nt,
                       ii*(n_inner+1) + jj + 1, tid);
        } // jj

        // ---- outer step ----
        const int j = tid & 15, nb = tid >> 4;
        // O1: project F (write sF, sFT)
        {
            #pragma unroll
            for (int rep = 0; rep < 4; rep++){
                int n = nb + rep*16;
                cf f = sF[n*F_S+j];
                float mag = hypotf(f.x, f.y);
                cf fp = (mag > 1e-12f) ? mkc(f.x/mag, f.y/mag) : mkc(0.f, 0.f);
                sF[n*F_S+j] = fp;
                sFT[j*FT_S+n] = fp;
            }
        }
        __syncthreads();
        // O2: MF = Mm@F_proj ; u = conj(H)@F_proj  (Vm = conj(u))
        computeMF_T(sMm, sFT, sMF, tid);
        uRefresh(sH, sFT, sU, tid);
        __syncthreads();
        // O3: FHMF + tr partial ; coef via shuffles
        float ptr2;
        {
            int i = tid >> 4;
            const float4* fti = (const float4*)(sFT + i*FT_S);
            cf acc = mkc(0,0);
            #pragma unroll
            for (int q = 0; q < 32; q++){
                float4 fv = fti[q];
                cmadc(acc, lo4(fv), sMF[(2*q  )*F_S+j]);
                cmadc(acc, hi4(fv), sMF[(2*q+1)*F_S+j]);
            }
            sFHMF[i*17+j] = acc;
            cf v = sV[j*16+i];
            ptr2 = acc.x*v.x - acc.y*v.y;
        }
        if (tid < 128){
            int m = tid >> 4, r = tid & 15;
            cf u_mr = sU[m*U_S+r];
            const float4* up = (const float4*)(sU + m*U_S);
            cf t2 = mkc(0,0);
            #pragma unroll
            for (int q = 0; q < 8; q++){
                float4 uv = up[q];
                cmad_cc(t2, sV[(2*q)*16+r],   lo4(uv));
                cmad_cc(t2, sV[(2*q+1)*16+r], hi4(uv));
            }
            float trm = u_mr.x*t2.x - u_mr.y*t2.y;
            cf a = mkc(0,0); cmad(a, u_mr, sW[r*8+m]);
            #pragma unroll
            for (int mask = 8; mask >= 1; mask >>= 1){
                trm += __shfl_xor(trm, mask, 16);
                a.x += __shfl_xor(a.x, mask, 16);
                a.y += __shfl_xor(a.y, mask, 16);
            }
            if (r == 0){
                float invd = 1.0f/(LN2F*(trm + 1.0f)*8.0f);
                sCoefC[m] = mkc(a.x*invd, a.y*invd);
            }
        }
        float trW = blockReduceSum(ptr2, sRed+0, tid);
        // O5a: gW in regs
        cf gw = mkc(0,0);
        if (tid < 128){
            int i2 = tid >> 3, mm = tid & 7;
            cf acc = mkc(0,0);
            #pragma unroll
            for (int j2 = 0; j2 < 16; j2++) cmad(acc, sFHMF[i2*17+j2], sW[j2*8+mm]);
            float hinv = 0.5f / trW;
            gw = mkc(acc.x*hinv, acc.y*hinv);
            cmadc(gw, sU[mm*U_S+i2], sCoefC[mm]);   // += conj(u)*coef
        }
        __syncthreads();
        // O6: RMSProp W update
        if (tid < 128){
            cf sw = ssw;
            sw.x = BETA_*sw.x + OMB_*gw.x;
            sw.y = BETA_*sw.y + OMB_*gw.y;
            ssw = sw;
            cf d = csqrtf2(sw); d.x += EPS_;
            cf upd = cdiv(gw, d);
            cf w = sW[tid];
            w.x = fmaf(ETAW_, upd.x, w.x);
            w.y = fmaf(ETAW_, upd.y, w.y);
            sW[tid] = w;
        }
        __syncthreads();
        // O7: FW + power -> s2
        float pw2 = blockReduceSum(fwPartial(sF, sW, sFW, tid), sRed+4, tid);
        float s2 = sqrtf(Pt / pw2);
        // O8: trc via MF@W_new
        float ptrc2 = trcViaMF(sMF, sW, sFW, tid);
        float trc2 = blockReduceSum(ptrc2, sRed+8, tid);
        // O9: scale W
        if (tid < 128){
            cf w = sW[tid];
            sW[tid] = mkc(w.x*s2, w.y*s2);
        }
        __syncthreads();
        // O10: tracking at slot 0 (sU valid: F unchanged since O2)
        ratesWrite(sU, sW, s2*s2*trc2, xi0, outR, outC, (size_t)b*nt,
                   ii*(n_inner+1), tid);
        __syncthreads();
    } // ii

    // ---- write final F, W ----
    if (cplx){
        int j = tid & 15, nb = tid >> 4;
        #pragma unroll
        for (int rep = 0; rep < 4; rep++){
            int n = nb + rep*16;
            cf f = sF[n*F_S+j];
            size_t o = ((size_t)b*1024 + (size_t)(tid + rep*256))*2;
            outF[o]   = f.x;
            outF[o+1] = f.y;
        }
        if (tid < 128){
            cf w = sW[tid];
            size_t o = ((size_t)b*128 + tid)*2;
            outW[o]   = w.x;
            outW[o+1] = w.y;
        }
    } else {
        int j = tid & 15, nb = tid >> 4;
        #pragma unroll
        for (int rep = 0; rep < 4; rep++){
            int n = nb + rep*16;
            outF[(size_t)b*1024 + (size_t)(tid + rep*256)] = sF[n*F_S+j].x;
        }
        if (tid < 128)
            outW[(size_t)b*128 + tid] = sW[tid].x;
    }
}

extern "C" void kernel_launch(void* const* d_in, const int* in_sizes, int n_in,
                              void* d_out, int out_size, void* d_ws, size_t ws_size,
                              hipStream_t stream)
{
    (void)n_in;
    int B = in_sizes[0] / 512;   // A*B*Mu*N / (8*64)

    // Infer output layout for complex64 F/W: 2 floats/elem (interleaved) or 1 (real-only).
    long S = (long)out_size;
    long numI = S - 2304L*B;
    long numR = S - 1152L*B;
    bool okI = (numI > 0) && (numI % (2L*B) == 0) && (numI/(2L*B) >= 1) && (numI/(2L*B) <= 256);
    bool okR = (numR > 0) && (numR % (2L*B) == 0) && (numR/(2L*B) >= 1) && (numR/(2L*B) <= 256);
    int cplx = okI ? 1 : (okR ? 0 : 1);

    const float* Ar = (const float*)d_in[6];
    const float* Ai = (const float*)d_in[7];
    const float* Rr = (const float*)d_in[8];
    const float* Ri = (const float*)d_in[9];

    cf* Mm = nullptr;
    if (d_ws != nullptr && ws_size >= 65536){
        Mm = (cf*)d_ws;
        pga_prep<<<1, 256, 0, stream>>>(Ar, Ai, Rr, Ri, Mm);
    }

    pga_main<<<B, 256, 0, stream>>>(
        (const float*)d_in[0], (const float*)d_in[1],
        (const float*)d_in[2], (const float*)d_in[3],
        (const float*)d_in[4], (const float*)d_in[5],
        Ar, Ai, Rr, Ri,
        Mm,
        (const float*)d_in[10],
        (const int*)d_in[11], (const int*)d_in[12], (const int*)d_in[13],
        (float*)d_out, B, cplx);
}

// Round 5
// 991.277 us; speedup vs baseline: 1.7450x; 1.0801x over previous
//
#include <hip/hip_runtime.h>
#include <math.h>

// ---------------- complex helpers (float2 = re,im) ----------------
typedef float2 cf;

__device__ __forceinline__ cf mkc(float x, float y){ return make_float2(x,y); }
__device__ __forceinline__ cf lo4(float4 v){ return mkc(v.x, v.y); }
__device__ __forceinline__ cf hi4(float4 v){ return mkc(v.z, v.w); }

// acc += a*b
__device__ __forceinline__ void cmad(cf& acc, cf a, cf b){
    acc.x = fmaf(a.x, b.x, fmaf(-a.y, b.y, acc.x));
    acc.y = fmaf(a.x, b.y, fmaf( a.y, b.x, acc.y));
}
// acc += conj(a)*b
__device__ __forceinline__ void cmadc(cf& acc, cf a, cf b){
    acc.x = fmaf(a.x, b.x, fmaf( a.y, b.y, acc.x));
    acc.y = fmaf(a.x, b.y, fmaf(-a.y, b.x, acc.y));
}
// acc += a*conj(b)
__device__ __forceinline__ void cmad_bc(cf& acc, cf a, cf b){
    acc.x = fmaf(a.x, b.x, fmaf( a.y, b.y, acc.x));
    acc.y = fmaf(a.y, b.x, fmaf(-a.x, b.y, acc.y));
}
// acc += conj(a)*conj(b)
__device__ __forceinline__ void cmad_cc(cf& acc, cf a, cf b){
    acc.x = fmaf(a.x, b.x, fmaf(-a.y, b.y, acc.x));
    acc.y = fmaf(-a.x, b.y, fmaf(-a.y, b.x, acc.y));
}
// principal complex sqrt (numpy branch conventions)
__device__ __forceinline__ cf csqrtf2(cf z){
    float x = z.x, y = z.y;
    float r = hypotf(x, y);
    if (r == 0.0f) return mkc(0.f, 0.f);
    if (x >= 0.0f){
        float t = sqrtf(0.5f*(r + x));
        return mkc(t, 0.5f*y/t);
    } else {
        float t = sqrtf(0.5f*(r - x));
        return mkc(0.5f*fabsf(y)/t, copysignf(t, y));
    }
}
// a / b
__device__ __forceinline__ cf cdiv(cf a, cf b){
    float inv = 1.0f/(b.x*b.x + b.y*b.y);
    return mkc((a.x*b.x + a.y*b.y)*inv, (a.y*b.x - a.x*b.y)*inv);
}

#define LN2F  0.69314718055994530942f
#define BETA_ 0.9f
#define OMB_  0.1f
#define EPS_  1e-8f
#define ETAF_ 0.01f
#define ETAW_ 0.01f

#define MM_S 66   /* sMm row stride (cf) */
#define F_S  18   /* sF / sMF row stride */
#define FT_S 66   /* sFT row stride */
#define H_S  66   /* sH row stride */
#define U_S  18   /* sU row stride */
#define V_S  18   /* sV row stride */

__device__ __forceinline__ float readScalarF(const int* p){
    int iv = *p;
    if (iv >= 0 && iv < 1000000) return (float)iv;
    return __int_as_float(iv);
}
__device__ __forceinline__ int readScalarI(const int* p){
    int iv = *p;
    if (iv >= 0 && iv < 1000000) return iv;
    return (int)(__int_as_float(iv) + 0.5f);
}

__device__ __forceinline__ float blockReduceSum(float v, float* slot, int tid){
    #pragma unroll
    for (int o = 32; o > 0; o >>= 1) v += __shfl_down(v, o, 64);
    if ((tid & 63) == 0) slot[tid >> 6] = v;
    __syncthreads();
    return slot[0] + slot[1] + slot[2] + slot[3];
}
// two sums, one barrier
__device__ __forceinline__ float2 blockReduceSum2(float a, float b2, float* sA, float* sB, int tid){
    #pragma unroll
    for (int o = 32; o > 0; o >>= 1){ a += __shfl_down(a, o, 64); b2 += __shfl_down(b2, o, 64); }
    if ((tid & 63) == 0){ sA[tid >> 6] = a; sB[tid >> 6] = b2; }
    __syncthreads();
    return make_float2(sA[0]+sA[1]+sA[2]+sA[3], sB[0]+sB[1]+sB[2]+sB[3]);
}

// MF = Mm @ F via FT (row-contiguous b128). thread (nb=tid>>4, j=tid&15), 4 rows.
__device__ __forceinline__ void computeMF_T(const cf* sMm, const cf* sFT, cf* sMF, int tid){
    int j = tid & 15, nb = tid >> 4;
    cf a0=mkc(0,0), a1=mkc(0,0), a2=mkc(0,0), a3=mkc(0,0);
    const float4* ftrow = (const float4*)(sFT + j*FT_S);
    #pragma unroll
    for (int kkb = 0; kkb < 4; kkb++){
        cf f[16];
        #pragma unroll
        for (int q = 0; q < 8; q++){
            float4 v = ftrow[kkb*8+q];
            f[2*q] = lo4(v); f[2*q+1] = hi4(v);
        }
        const float4* m0 = (const float4*)(sMm + (nb    )*MM_S + kkb*16);
        const float4* m1 = (const float4*)(sMm + (nb+16 )*MM_S + kkb*16);
        const float4* m2 = (const float4*)(sMm + (nb+32 )*MM_S + kkb*16);
        const float4* m3 = (const float4*)(sMm + (nb+48 )*MM_S + kkb*16);
        #pragma unroll
        for (int q = 0; q < 8; q++){
            float4 v0 = m0[q], v1 = m1[q], v2 = m2[q], v3 = m3[q];
            cmad(a0, lo4(v0), f[2*q]); cmad(a0, hi4(v0), f[2*q+1]);
            cmad(a1, lo4(v1), f[2*q]); cmad(a1, hi4(v1), f[2*q+1]);
            cmad(a2, lo4(v2), f[2*q]); cmad(a2, hi4(v2), f[2*q+1]);
            cmad(a3, lo4(v3), f[2*q]); cmad(a3, hi4(v3), f[2*q+1]);
        }
    }
    sMF[(nb   )*F_S+j]=a0; sMF[(nb+16)*F_S+j]=a1;
    sMF[(nb+32)*F_S+j]=a2; sMF[(nb+48)*F_S+j]=a3;
}

// u[m][j] = sum_n conj(H[m,n]) F[n,j], split-K over 256 threads (interleaved chunks)
__device__ __forceinline__ void uRefresh(const cf* sH, const cf* sFT, cf* sU, int tid){
    int h = tid & 1, j = (tid >> 1) & 15, m = tid >> 5;
    const float4* hp = (const float4*)(sH  + m*H_S);
    const float4* fp = (const float4*)(sFT + j*FT_S);
    cf acc = mkc(0,0);
    #pragma unroll
    for (int q = 0; q < 16; q++){
        int c = 2*q + h;
        float4 hv = hp[c], fv = fp[c];
        cmadc(acc, lo4(hv), lo4(fv));
        cmadc(acc, hi4(hv), hi4(fv));
    }
    acc.x += __shfl_xor(acc.x, 1, 64);
    acc.y += __shfl_xor(acc.y, 1, 64);
    if (h == 0) sU[m*U_S+j] = acc;
}

// FW = F@W (rows of sF as b128), returns |FW|^2 partial
__device__ __forceinline__ float fwPartial(const cf* sF, const cf* sW, cf* sFW, int tid){
    int k = tid & 7, nb = tid >> 3;
    cf wcol[16];
    #pragma unroll
    for (int r = 0; r < 16; r++) wcol[r] = sW[r*8+k];
    float part = 0.f;
    #pragma unroll
    for (int rep = 0; rep < 2; rep++){
        int n = nb + rep*32;
        const float4* fr = (const float4*)(sF + n*F_S);
        cf acc = mkc(0,0);
        #pragma unroll
        for (int q = 0; q < 8; q++){
            float4 v = fr[q];
            cmad(acc, lo4(v), wcol[2*q]); cmad(acc, hi4(v), wcol[2*q+1]);
        }
        sFW[n*8+k] = acc;
        part += acc.x*acc.x + acc.y*acc.y;
    }
    return part;
}

// trc partial via Y = MF@W: sum Re(conj(FW)*(MF@W)); reads own-thread sFW
__device__ __forceinline__ float trcViaMF(const cf* sMF, const cf* sW, const cf* sFW, int tid){
    int k = tid & 7, nb = tid >> 3;
    cf wcol[16];
    #pragma unroll
    for (int r = 0; r < 16; r++) wcol[r] = sW[r*8+k];
    float ptrc = 0.f;
    #pragma unroll
    for (int rep = 0; rep < 2; rep++){
        int n = nb + rep*32;
        const float4* mr = (const float4*)(sMF + n*F_S);
        cf acc = mkc(0,0);
        #pragma unroll
        for (int q = 0; q < 8; q++){
            float4 v = mr[q];
            cmad(acc, lo4(v), wcol[2*q]); cmad(acc, hi4(v), wcol[2*q+1]);
        }
        cf fw = sFW[n*8+k];
        ptrc += fw.x*acc.x + fw.y*acc.y;
    }
    return ptrc;
}

// sum-rate on wave 3 (tid>=192); mul = scale^2 applied inside log; result -> *sRateVal
__device__ __forceinline__ void ratesWave3(const cf* sU, const cf* sW, float mul,
                                           float* sRateVal, int tid){
    if (tid < 192) return;
    int l = tid - 192, m = l >> 3, k = l & 7;
    cf acc = mkc(0,0);
    #pragma unroll
    for (int j = 0; j < 16; j++) cmad(acc, sU[m*U_S+j], sW[j*8+k]);
    float p = acc.x*acc.x + acc.y*acc.y;
    float tot = p;
    #pragma unroll
    for (int mask = 4; mask >= 1; mask >>= 1) tot += __shfl_xor(tot, mask, 8);
    float sig = __shfl(p, 9*m, 64);
    float rate = log2f(1.0f + (mul*sig)/fmaf(mul, tot - sig, 1.0f));
    float val = (k == 0) ? rate : 0.0f;
    #pragma unroll
    for (int mask = 32; mask >= 1; mask >>= 1) val += __shfl_xor(val, mask, 64);
    if (l == 0) *sRateVal = val;
}

// ---------------- optional prep: Mm = A_dot^H @ R_N_inv @ A_dot -> ws ----------------
__global__ __launch_bounds__(256) void pga_prep(
    const float* __restrict__ Ar, const float* __restrict__ Ai,
    const float* __restrict__ Rr, const float* __restrict__ Ri,
    cf* __restrict__ Mm)
{
    __shared__ cf sA[4096];
    __shared__ cf Tc[512];
    int tid = threadIdx.x;
    for (int idx = tid; idx < 4096; idx += 256)
        sA[idx] = mkc(Ar[idx], Ai[idx]);
    __syncthreads();
    for (int jb = 0; jb < 8; jb++){
        int j0 = jb*8;
        #pragma unroll
        for (int rep = 0; rep < 2; rep++){
            int idx = tid + rep*256;
            int p = idx >> 3, jc = idx & 7;
            cf acc = mkc(0,0);
            for (int q = 0; q < 64; q++){
                cf rv = mkc(Rr[p*64+q], Ri[p*64+q]);
                cmad(acc, rv, sA[q*64 + j0 + jc]);
            }
            Tc[idx] = acc;
        }
        __syncthreads();
        #pragma unroll
        for (int rep = 0; rep < 2; rep++){
            int idx = tid + rep*256;
            int i = idx >> 3, jc = idx & 7;
            cf acc = mkc(0,0);
            for (int p = 0; p < 64; p++)
                cmadc(acc, sA[p*64+i], Tc[p*8+jc]);
            Mm[i*64 + j0 + jc] = acc;
        }
        __syncthreads();
    }
}

// ---------------- main kernel ----------------
__global__ __launch_bounds__(256) void pga_main(
    const float* __restrict__ Hre, const float* __restrict__ Him,
    const float* __restrict__ F0re, const float* __restrict__ F0im,
    const float* __restrict__ W0re, const float* __restrict__ W0im,
    const float* __restrict__ Ar, const float* __restrict__ Ai,
    const float* __restrict__ Rr, const float* __restrict__ Ri,
    const cf* __restrict__ MmGlobal,
    const float* __restrict__ xi0p,
    const int* __restrict__ Ptp, const int* __restrict__ noutp, const int* __restrict__ ninnp,
    float* __restrict__ out, int B, int cplx)
{
    const int tid = threadIdx.x;
    const int b = blockIdx.x;

    __shared__ __align__(16) char sPool[76736];
    __shared__ float sRed[12];
    __shared__ float sRateVal;

    cf* sMm   = (cf*)(sPool + 0);       // 64 x 66  (33792 B)
    cf* sF    = (cf*)(sPool + 33792);   // 64 x 18  ( 9216 B)
    cf* sMF   = (cf*)(sPool + 43008);   // 64 x 18  ( 9216 B)
    cf* sFT   = (cf*)(sPool + 52224);   // 16 x 66  ( 8448 B)
    cf* sH    = (cf*)(sPool + 60672);   // 8 x 66   ( 4224 B)
    cf* sW    = (cf*)(sPool + 64896);   // [r*8+m]  ( 1024 B)
    cf* sV    = (cf*)(sPool + 65920);   // 16 x 18  ( 2304 B)
    cf* sU    = (cf*)(sPool + 68224);   // 8 x 18   ( 1152 B)
    cf* sRow  = (cf*)(sPool + 69376);   // [m*16+j] ( 1024 B)
    cf* sFHMF = (cf*)(sPool + 70400);   // 16 x 17  ( 2176 B)
    cf* sFW   = (cf*)(sPool + 72576);   // [n*8+k]  ( 4096 B)
    cf* sCoefC= (cf*)(sPool + 76672);   // [8]      (   64 B)

    const float Pt    = readScalarF(Ptp);
    const int n_outer = readScalarI(noutp);
    const int n_inner = readScalarI(ninnp);
    const float xi0   = xi0p[0];
    const int nt = n_outer * (n_inner + 1);
    const float cxi = 2.0f*xi0*xi0;

    float* outR = out;
    float* outC = out + (size_t)B * nt;
    float* outF = out + (size_t)2 * B * nt;
    float* outW = outF + (cplx ? (size_t)B * 2048 : (size_t)B * 1024);

    // ---- Mm into LDS ----
    if (MmGlobal){
        for (int idx = tid; idx < 4096; idx += 256){
            int r = idx >> 6, c = idx & 63;
            sMm[r*MM_S+c] = MmGlobal[idx];
        }
    } else {
        cf* sA = (cf*)(sPool + 33792);   // overlay
        cf* Tc = (cf*)(sPool + 66560);   // overlay
        for (int idx = tid; idx < 4096; idx += 256)
            sA[idx] = mkc(Ar[idx], Ai[idx]);
        __syncthreads();
        for (int jb = 0; jb < 8; jb++){
            int j0 = jb*8;
            #pragma unroll
            for (int rep = 0; rep < 2; rep++){
                int idx = tid + rep*256;
                int p = idx >> 3, jc = idx & 7;
                cf acc = mkc(0,0);
                for (int q = 0; q < 64; q++){
                    cf rv = mkc(Rr[p*64+q], Ri[p*64+q]);
                    cmad(acc, rv, sA[q*64 + j0 + jc]);
                }
                Tc[idx] = acc;
            }
            __syncthreads();
            #pragma unroll
            for (int rep = 0; rep < 2; rep++){
                int idx = tid + rep*256;
                int i2 = idx >> 3, jc = idx & 7;
                cf acc = mkc(0,0);
                for (int p = 0; p < 64; p++)
                    cmadc(acc, sA[p*64+i2], Tc[p*8+jc]);
                sMm[i2*MM_S + j0 + jc] = acc;
            }
            __syncthreads();
        }
        __syncthreads();
    }

    // ---- load H, F (projected -> sF & sFT), W ----
    cf fsf[4]; cf ssw = mkc(0.f, 0.f);
    {
        const float* hr = Hre + (size_t)b*512;
        const float* hi = Him + (size_t)b*512;
        for (int idx = tid; idx < 512; idx += 256){
            int m = idx >> 6, n = idx & 63;
            sH[m*H_S+n] = mkc(hr[idx], hi[idx]);
        }
        const float* fr = F0re + (size_t)b*1024;
        const float* fi = F0im + (size_t)b*1024;
        for (int idx = tid; idx < 1024; idx += 256){
            int n = idx >> 4, r = idx & 15;
            float re = fr[idx], im = fi[idx];
            float mag = hypotf(re, im);
            cf f = (mag > 1e-12f) ? mkc(re/mag, im/mag) : mkc(0.f, 0.f);
            sF[n*F_S+r] = f;
            sFT[r*FT_S+n] = f;
        }
        if (tid < 128)
            sW[tid] = mkc(W0re[(size_t)b*128 + tid], W0im[(size_t)b*128 + tid]);
        #pragma unroll
        for (int rep = 0; rep < 4; rep++) fsf[rep] = mkc(0.f, 0.f);
    }
    __syncthreads();

    // ---- init: u, W-normalize, MF ----
    uRefresh(sH, sFT, sU, tid);
    {
        float pw0 = blockReduceSum(fwPartial(sF, sW, sFW, tid), sRed+0, tid);
        float s0 = sqrtf(Pt / pw0);
        if (tid < 128){ cf w = sW[tid]; sW[tid] = mkc(w.x*s0, w.y*s0); }
    }
    computeMF_T(sMm, sFT, sMF, tid);
    __syncthreads();

    float sp = 1.0f, sp2 = 1.0f;   // pending normalize scale of F (true F = sp * stored F)

    for (int ii = 0; ii < n_outer; ii++){
        // V = W W^H
        {
            int i = tid >> 4, jx = tid & 15;
            cf acc = mkc(0,0);
            #pragma unroll
            for (int k = 0; k < 8; k++) cmad_bc(acc, sW[i*8+k], sW[jx*8+k]);
            sV[i*V_S+jx] = acc;
        }
        __syncthreads();

        for (int jj = 0; jj < n_inner; jj++){
            const int j = tid & 15, nb = tid >> 4;

            // V row j into regs (V Hermitian: column j = conj(row j))
            cf vrow[16];
            {
                const float4* vp = (const float4*)(sV + j*V_S);
                #pragma unroll
                for (int q = 0; q < 8; q++){
                    float4 v = vp[q];
                    vrow[2*q] = lo4(v); vrow[2*q+1] = hi4(v);
                }
            }
            // G = MF@V (regs) + trace partial
            float ptr_ = 0.f;
            cf G[4];
            #pragma unroll
            for (int rep = 0; rep < 4; rep++){
                int n = nb + rep*16;
                const float4* mr = (const float4*)(sMF + n*F_S);
                cf acc = mkc(0,0);
                #pragma unroll
                for (int q = 0; q < 8; q++){
                    float4 v = mr[q];
                    cmad_bc(acc, lo4(v), vrow[2*q]); cmad_bc(acc, hi4(v), vrow[2*q+1]);
                }
                G[rep] = acc;
                cf f = sF[n*F_S+j];
                ptr_ += f.x*acc.x + f.y*acc.y;
            }
            // coef/row (tid<128), with sp-folded scaling
            if (tid < 128){
                int m = tid >> 4;
                const float4* up = (const float4*)(sU + m*U_S);
                cf t2 = mkc(0,0);
                #pragma unroll
                for (int q = 0; q < 8; q++){
                    float4 uv = up[q];
                    cmad_bc(t2, lo4(uv), vrow[2*q]); cmad_bc(t2, hi4(uv), vrow[2*q+1]);
                }
                cf u = sU[m*U_S+j];
                float qv = t2.x*u.x + t2.y*u.y;
                cf c = mkc(0,0); cmad(c, u, sW[j*8+m]);
                #pragma unroll
                for (int mask = 8; mask >= 1; mask >>= 1){
                    qv  += __shfl_xor(qv,  mask, 16);
                    c.x += __shfl_xor(c.x, mask, 16);
                    c.y += __shfl_xor(c.y, mask, 16);
                }
                float cc = c.x*c.x + c.y*c.y;
                float inv1 = 1.0f/(LN2F*(sp2*qv + 1.0f) + 1e-4f);
                float inv2 = 1.0f/(LN2F*(sp2*(qv - cc) + 1.0f) + 1e-4f);
                float a = inv1 - inv2;
                cf ci = mkc(c.x*inv2, c.y*inv2);
                cf row = mkc(t2.x*a, t2.y*a);
                cmad_bc(row, ci, sW[j*8+m]);
                sRow[tid] = row;                 // true row = sp * stored
            }
            // delayed tracking (state of previous inner iter) on wave 3
            if (jj > 0) ratesWave3(sU, sW, sp2, &sRateVal, tid);
            float tr = blockReduceSum(ptr_, sRed+0, tid);   // barrier B1
            if (jj > 0 && tid == 0){
                int t = ii*(n_inner+1) + jj;
                size_t base = (size_t)b*nt;
                outR[base + t] = sRateVal;
                outC[base + t] = 1.0f/(cxi*(sp2*tr) + 1e-12f);
            }

            // D: gF (sp-folded) + RMSProp + F update
            {
                float hinv = 0.5f/(sp*tr);
                cf rowj[8];
                #pragma unroll
                for (int m = 0; m < 8; m++){
                    cf r = sRow[m*16+j];
                    rowj[m] = mkc(sp*r.x, sp*r.y);
                }
                #pragma unroll
                for (int rep = 0; rep < 4; rep++){
                    int n = nb + rep*16;
                    cf g = mkc(G[rep].x*hinv, G[rep].y*hinv);
                    #pragma unroll
                    for (int m = 0; m < 8; m++) cmad(g, sH[m*H_S+n], rowj[m]);
                    cf sf = fsf[rep];
                    sf.x = BETA_*sf.x + OMB_*g.x;
                    sf.y = BETA_*sf.y + OMB_*g.y;
                    fsf[rep] = sf;
                    cf d = csqrtf2(sf); d.x += EPS_;
                    cf upd = cdiv(g, d);
                    cf f = sF[n*F_S+j];
                    cf fn = mkc(fmaf(ETAF_, upd.x, sp*f.x), fmaf(ETAF_, upd.y, sp*f.y));
                    sF[n*F_S+j] = fn;
                    sFT[j*FT_S+n] = fn;
                }
            }
            __syncthreads();                                 // barrier B2

            // E: MF recompute, FW/power partial, u refresh
            computeMF_T(sMm, sFT, sMF, tid);
            float part = fwPartial(sF, sW, sFW, tid);
            uRefresh(sH, sFT, sU, tid);
            float pw = blockReduceSum(part, sRed+4, tid);    // barrier B3
            float s = sqrtf(Pt / pw);
            sp = s; sp2 = s*s;

            // last inner iter: explicit trace + tracking (no following G phase)
            if (jj == n_inner-1){
                float ptrl = 0.f;
                #pragma unroll
                for (int rep = 0; rep < 4; rep++){
                    int n = nb + rep*16;
                    const float4* mr = (const float4*)(sMF + n*F_S);
                    cf acc = mkc(0,0);
                    #pragma unroll
                    for (int q = 0; q < 8; q++){
                        float4 v = mr[q];
                        cmad_bc(acc, lo4(v), vrow[2*q]); cmad_bc(acc, hi4(v), vrow[2*q+1]);
                    }
                    cf f = sF[n*F_S+j];
                    ptrl += f.x*acc.x + f.y*acc.y;
                }
                ratesWave3(sU, sW, sp2, &sRateVal, tid);
                float trl = blockReduceSum(ptrl, sRed+8, tid); // barrier B4
                if (tid == 0){
                    int t = ii*(n_inner+1) + n_inner;
                    size_t base = (size_t)b*nt;
                    outR[base + t] = sRateVal;
                    outC[base + t] = 1.0f/(cxi*(sp2*trl) + 1e-12f);
                }
            }
        } // jj

        // ---- outer step ----
        const int j = tid & 15, nb = tid >> 4;
        // O1: project F (scale-invariant; threshold on true magnitude)
        {
            #pragma unroll
            for (int rep = 0; rep < 4; rep++){
                int n = nb + rep*16;
                cf f = sF[n*F_S+j];
                float mag = hypotf(f.x, f.y);
                cf fp = (sp*mag > 1e-12f) ? mkc(f.x/mag, f.y/mag) : mkc(0.f, 0.f);
                sF[n*F_S+j] = fp;
                sFT[j*FT_S+n] = fp;
            }
            sp = 1.0f; sp2 = 1.0f;
        }
        __syncthreads();
        // O2: MF = Mm@F_proj ; u = conj(H)@F_proj
        computeMF_T(sMm, sFT, sMF, tid);
        uRefresh(sH, sFT, sU, tid);
        __syncthreads();
        // O3: FHMF + tr partial ; coef via shuffles
        float ptr2;
        {
            int i = tid >> 4;
            const float4* fti = (const float4*)(sFT + i*FT_S);
            cf acc = mkc(0,0);
            #pragma unroll
            for (int q = 0; q < 32; q++){
                float4 fv = fti[q];
                cmadc(acc, lo4(fv), sMF[(2*q  )*F_S+j]);
                cmadc(acc, hi4(fv), sMF[(2*q+1)*F_S+j]);
            }
            sFHMF[i*17+j] = acc;
            cf v = sV[j*V_S+i];
            ptr2 = acc.x*v.x - acc.y*v.y;
        }
        if (tid < 128){
            int m = tid >> 4, r = tid & 15;
            cf u_mr = sU[m*U_S+r];
            const float4* up = (const float4*)(sU + m*U_S);
            cf t2 = mkc(0,0);
            #pragma unroll
            for (int q = 0; q < 8; q++){
                float4 uv = up[q];
                cmad_cc(t2, sV[(2*q)*V_S+r],   lo4(uv));
                cmad_cc(t2, sV[(2*q+1)*V_S+r], hi4(uv));
            }
            float trm = u_mr.x*t2.x - u_mr.y*t2.y;
            cf a = mkc(0,0); cmad(a, u_mr, sW[r*8+m]);
            #pragma unroll
            for (int mask = 8; mask >= 1; mask >>= 1){
                trm += __shfl_xor(trm, mask, 16);
                a.x += __shfl_xor(a.x, mask, 16);
                a.y += __shfl_xor(a.y, mask, 16);
            }
            if (r == 0){
                float invd = 1.0f/(LN2F*(trm + 1.0f)*8.0f);
                sCoefC[m] = mkc(a.x*invd, a.y*invd);
            }
        }
        float trW = blockReduceSum(ptr2, sRed+0, tid);
        // O5a: gW in regs
        cf gw = mkc(0,0);
        if (tid < 128){
            int i2 = tid >> 3, mm = tid & 7;
            cf acc = mkc(0,0);
            #pragma unroll
            for (int j2 = 0; j2 < 16; j2++) cmad(acc, sFHMF[i2*17+j2], sW[j2*8+mm]);
            float hinv = 0.5f / trW;
            gw = mkc(acc.x*hinv, acc.y*hinv);
            cmadc(gw, sU[mm*U_S+i2], sCoefC[mm]);
        }
        __syncthreads();
        // O6: RMSProp W update
        if (tid < 128){
            cf sw = ssw;
            sw.x = BETA_*sw.x + OMB_*gw.x;
            sw.y = BETA_*sw.y + OMB_*gw.y;
            ssw = sw;
            cf d = csqrtf2(sw); d.x += EPS_;
            cf upd = cdiv(gw, d);
            cf w = sW[tid];
            w.x = fmaf(ETAW_, upd.x, w.x);
            w.y = fmaf(ETAW_, upd.y, w.y);
            sW[tid] = w;
        }
        __syncthreads();
        // O7/O8: power + crb trace, one dual reduce
        float part2 = fwPartial(sF, sW, sFW, tid);
        float ptrc2 = trcViaMF(sMF, sW, sFW, tid);
        float2 pr = blockReduceSum2(part2, ptrc2, sRed+4, sRed+8, tid);
        float s2 = sqrtf(Pt / pr.x);
        float s2sq = s2*s2;
        // rates on pre-scale W with mul = s2^2
        ratesWave3(sU, sW, s2sq, &sRateVal, tid);
        __syncthreads();
        // O9/O10: scale W, write tracking slot ii*(n_inner+1)
        if (tid < 128){
            cf w = sW[tid];
            sW[tid] = mkc(w.x*s2, w.y*s2);
        }
        if (tid == 0){
            int t = ii*(n_inner+1);
            size_t base = (size_t)b*nt;
            outR[base + t] = sRateVal;
            outC[base + t] = 1.0f/(cxi*(s2sq*pr.y) + 1e-12f);
        }
        __syncthreads();
    } // ii

    // ---- write final F (projected, true), W (scaled) ----
    if (cplx){
        int j = tid & 15, nb = tid >> 4;
        #pragma unroll
        for (int rep = 0; rep < 4; rep++){
            int n = nb + rep*16;
            cf f = sF[n*F_S+j];
            size_t o = ((size_t)b*1024 + (size_t)(tid + rep*256))*2;
            outF[o]   = f.x;
            outF[o+1] = f.y;
        }
        if (tid < 128){
            cf w = sW[tid];
            size_t o = ((size_t)b*128 + tid)*2;
            outW[o]   = w.x;
            outW[o+1] = w.y;
        }
    } else {
        int j = tid & 15, nb = tid >> 4;
        #pragma unroll
        for (int rep = 0; rep < 4; rep++){
            int n = nb + rep*16;
            outF[(size_t)b*1024 + (size_t)(tid + rep*256)] = sF[n*F_S+j].x;
        }
        if (tid < 128)
            outW[(size_t)b*128 + tid] = sW[tid].x;
    }
}

extern "C" void kernel_launch(void* const* d_in, const int* in_sizes, int n_in,
                              void* d_out, int out_size, void* d_ws, size_t ws_size,
                              hipStream_t stream)
{
    (void)n_in;
    int B = in_sizes[0] / 512;   // A*B*Mu*N / (8*64)

    long S = (long)out_size;
    long numI = S - 2304L*B;
    long numR = S - 1152L*B;
    bool okI = (numI > 0) && (numI % (2L*B) == 0) && (numI/(2L*B) >= 1) && (numI/(2L*B) <= 256);
    bool okR = (numR > 0) && (numR % (2L*B) == 0) && (numR/(2L*B) >= 1) && (numR/(2L*B) <= 256);
    int cplx = okI ? 1 : (okR ? 0 : 1);

    const float* Ar = (const float*)d_in[6];
    const float* Ai = (const float*)d_in[7];
    const float* Rr = (const float*)d_in[8];
    const float* Ri = (const float*)d_in[9];

    cf* Mm = nullptr;
    if (d_ws != nullptr && ws_size >= 65536){
        Mm = (cf*)d_ws;
        pga_prep<<<1, 256, 0, stream>>>(Ar, Ai, Rr, Ri, Mm);
    }

    pga_main<<<B, 256, 0, stream>>>(
        (const float*)d_in[0], (const float*)d_in[1],
        (const float*)d_in[2], (const float*)d_in[3],
        (const float*)d_in[4], (const float*)d_in[5],
        Ar, Ai, Rr, Ri,
        Mm,
        (const float*)d_in[10],
        (const int*)d_in[11], (const int*)d_in[12], (const int*)d_in[13],
        (float*)d_out, B, cplx);
}